// Round 12
// baseline (174.831 us; speedup 1.0000x reference)
//
#include <hip/hip_runtime.h>
#include <math.h>

#define N_TOK 8192
#define C_DIM 128
#define NHD   8
#define HDIM  16
#define NR    1024
#define EPSV  1e-5f
#define QK_SCALE 0.25f
#define QK_L2E  0.36067376f   /* 0.25 * log2(e) */

typedef __attribute__((ext_vector_type(8))) short short8;
typedef __attribute__((ext_vector_type(4))) float f32x4;

__device__ __forceinline__ float gelu_f(float v) {
    float u = 0.7978845608f * (v + 0.044715f * v * v * v);
    float e = exp2f(2.885390082f * u);
    return v * (e / (e + 1.0f));
}
__device__ __forceinline__ float uaf(unsigned int u) {
    union { unsigned int u; float f; } x; x.u = u; return x.f;
}
__device__ __forceinline__ short f2b(float v) {
    union { float f; unsigned int u; } x; x.f = v;
    unsigned int r = x.u + 0x7fffu + ((x.u >> 16) & 1u);
    return (short)(r >> 16);
}
__device__ __forceinline__ unsigned int pk2(float a, float b) {
    return (unsigned int)(unsigned short)f2b(a) | ((unsigned int)(unsigned short)f2b(b) << 16);
}
__device__ __forceinline__ void ld16bf(const short* p, float* d) {
    uint4 a = *(const uint4*)p;
    uint4 b = *(const uint4*)(p + 8);
    d[0]  = uaf(a.x << 16); d[1]  = uaf(a.x & 0xffff0000u);
    d[2]  = uaf(a.y << 16); d[3]  = uaf(a.y & 0xffff0000u);
    d[4]  = uaf(a.z << 16); d[5]  = uaf(a.z & 0xffff0000u);
    d[6]  = uaf(a.w << 16); d[7]  = uaf(a.w & 0xffff0000u);
    d[8]  = uaf(b.x << 16); d[9]  = uaf(b.x & 0xffff0000u);
    d[10] = uaf(b.y << 16); d[11] = uaf(b.y & 0xffff0000u);
    d[12] = uaf(b.z << 16); d[13] = uaf(b.z & 0xffff0000u);
    d[14] = uaf(b.w << 16); d[15] = uaf(b.w & 0xffff0000u);
}
__device__ __forceinline__ void gload16(const void* g, void* l) {
    __builtin_amdgcn_global_load_lds(
        (const __attribute__((address_space(1))) unsigned int*)g,
        (__attribute__((address_space(3))) unsigned int*)l, 16, 0, 0);
}

struct CvtDesc { const float* src; short* dst; int n; int pad; };
struct CvtArgs { CvtDesc d[10]; };

// ============ shared 128x128 MFMA K-loop (async-staged, 2-phase) ============
__device__ __forceinline__ void mm128(const short* __restrict__ A, const short* __restrict__ W,
                                      int K, int m0, int n0, int t, char* smem,
                                      f32x4 acc[4][4]) {
    short* As0 = (short*)smem;
    short* Bs0 = (short*)(smem + 32768);
    int w = t >> 6, l = t & 63;
    auto STAGE = [&](int buf, int k0) {
        short* As = As0 + buf * 8192;
        short* Bs = Bs0 + buf * 8192;
#pragma unroll
        for (int c = 0; c < 4; ++c) {
            int g0 = c * 256 + w * 64;
            int g  = g0 + l;
            int row = g >> 3, ss = g & 7;
            int slot = ss ^ (row & 7);
            gload16(A + (size_t)(m0 + row) * K + k0 + slot * 8, As + g0 * 8);
            gload16(W + (size_t)(n0 + row) * K + k0 + slot * 8, Bs + g0 * 8);
        }
    };
    int wm = (w >> 1) * 64, wn = (w & 1) * 64;
    int NT = K >> 6;
    STAGE(0, 0);
    int cur = 0;
    for (int it = 0; it < NT; ++it) {
        if (it + 1 < NT) {
            STAGE(cur ^ 1, (it + 1) << 6);
            asm volatile("s_waitcnt vmcnt(8)" ::: "memory");
        } else {
            asm volatile("s_waitcnt vmcnt(0)" ::: "memory");
        }
        __builtin_amdgcn_s_barrier();
        short* As = As0 + cur * 8192;
        short* Bs = Bs0 + cur * 8192;
#pragma unroll
        for (int kk = 0; kk < 2; ++kk) {
            short8 af[4], bf[4];
            int sl = kk * 4 + (l >> 4);
#pragma unroll
            for (int mf = 0; mf < 4; ++mf) {
                int row = wm + mf * 16 + (l & 15);
                af[mf] = *(const short8*)(&As[row * 64 + (sl ^ (row & 7)) * 8]);
            }
#pragma unroll
            for (int nf = 0; nf < 4; ++nf) {
                int row = wn + nf * 16 + (l & 15);
                bf[nf] = *(const short8*)(&Bs[row * 64 + (sl ^ (row & 7)) * 8]);
            }
#pragma unroll
            for (int mf = 0; mf < 4; ++mf)
#pragma unroll
                for (int nf = 0; nf < 4; ++nf)
                    acc[mf][nf] = __builtin_amdgcn_mfma_f32_16x16x32_bf16(
                        af[mf], bf[nf], acc[mf][nf], 0, 0, 0);
        }
        asm volatile("s_waitcnt lgkmcnt(0)" ::: "memory");
        __builtin_amdgcn_sched_barrier(0);
        __builtin_amdgcn_s_barrier();
        cur ^= 1;
    }
}

// ---- epilogue: bf16 out (optionally gelu) ----
template <int GELU>
__device__ __forceinline__ void epi_bf16(f32x4 acc[4][4], const float* bias, short* out,
                                         int m0, int n0, int N, int t) {
    int w = t >> 6, l = t & 63;
    int wm = (w >> 1) * 64, wn = (w & 1) * 64;
#pragma unroll
    for (int mf = 0; mf < 4; ++mf)
#pragma unroll
        for (int nf = 0; nf < 4; ++nf) {
            int col = n0 + wn + nf * 16 + (l & 15);
#pragma unroll
            for (int j = 0; j < 4; ++j) {
                int row = m0 + wm + mf * 16 + (l >> 4) * 4 + j;
                float v = acc[mf][nf][j];
                if (GELU) v = gelu_f(v + bias[col]);
                out[(size_t)row * N + col] = f2b(v);
            }
        }
}

// ---- epilogue: f32 = acc + bias + res ----
__device__ __forceinline__ void epi_res(f32x4 acc[4][4], const float* bias, const float* res,
                                        float* out, int m0, int N, int t) {
    int w = t >> 6, l = t & 63;
    int wm = (w >> 1) * 64, wn = (w & 1) * 64;
#pragma unroll
    for (int mf = 0; mf < 4; ++mf)
#pragma unroll
        for (int nf = 0; nf < 4; ++nf) {
            int col = wn + nf * 16 + (l & 15);
#pragma unroll
            for (int j = 0; j < 4; ++j) {
                int row = m0 + wm + mf * 16 + (l >> 4) * 4 + j;
                float v = acc[mf][nf][j] + bias[col] + res[(size_t)row * N + col];
                out[(size_t)row * N + col] = v;
            }
        }
}

// ---- epilogue: proj + residual + LayerNorm fused (writes t1 f32 and t2 bf16) ----
__device__ __forceinline__ void proj_ln_epi(f32x4 acc[4][4], const float* bias,
        const float* res, float* t1, short* t2, const float* g, const float* b,
        int m0, int t, char* smem) {
    int w = t >> 6, l = t & 63;
    int wm = (w >> 1) * 64, wn = (w & 1) * 64;
    float* zl = (float*)smem;   // [64][129]
#pragma unroll
    for (int half = 0; half < 2; ++half) {
        if ((wm >> 6) == half) {
#pragma unroll
            for (int mf = 0; mf < 4; ++mf)
#pragma unroll
                for (int nf = 0; nf < 4; ++nf) {
                    int col = wn + nf * 16 + (l & 15);
#pragma unroll
                    for (int j = 0; j < 4; ++j) {
                        int row = wm + mf * 16 + (l >> 4) * 4 + j;
                        float v = acc[mf][nf][j] + bias[col] + res[(size_t)(m0 + row) * C_DIM + col];
                        t1[(size_t)(m0 + row) * C_DIM + col] = v;
                        zl[(row & 63) * 129 + col] = v;
                    }
                }
        }
        __syncthreads();
        {
            int r = t >> 2, seg = (t & 3) * 32;
            const float* zr = zl + r * 129 + seg;
            float vv[32];
            float s = 0.f, sq = 0.f;
#pragma unroll
            for (int i = 0; i < 32; ++i) { vv[i] = zr[i]; s += vv[i]; sq += vv[i] * vv[i]; }
            s += __shfl_xor(s, 1);  s += __shfl_xor(s, 2);
            sq += __shfl_xor(sq, 1); sq += __shfl_xor(sq, 2);
            float m = s * (1.0f / 128.0f);
            float var = sq * (1.0f / 128.0f) - m * m;
            float rsq = rsqrtf(var + EPSV);
            int tok = m0 + half * 64 + r;
            short* op = t2 + (size_t)tok * C_DIM + seg;
            float o[32];
#pragma unroll
            for (int i = 0; i < 32; ++i) o[i] = (vv[i] - m) * rsq * g[seg + i] + b[seg + i];
#pragma unroll
            for (int q = 0; q < 4; ++q) {
                uint4 u;
                u.x = pk2(o[q * 8 + 0], o[q * 8 + 1]);
                u.y = pk2(o[q * 8 + 2], o[q * 8 + 3]);
                u.z = pk2(o[q * 8 + 4], o[q * 8 + 5]);
                u.w = pk2(o[q * 8 + 6], o[q * 8 + 7]);
                *(uint4*)(op + q * 8) = u;
            }
        }
        __syncthreads();
    }
}

// ---- epilogue: fc2-global + residual + gate fused -> out (C,N) ----
__device__ __forceinline__ void gate_epi(f32x4 acc[4][4], const float* bias,
        const float* res, const float* locf, const float* xin, float* outp,
        int m0, int t, char* smem) {
    int w = t >> 6, l = t & 63;
    int wm = (w >> 1) * 64, wn = (w & 1) * 64;
    float* zl = (float*)smem;   // [64][129]
#pragma unroll
    for (int half = 0; half < 2; ++half) {
        if ((wm >> 6) == half) {
#pragma unroll
            for (int mf = 0; mf < 4; ++mf)
#pragma unroll
                for (int nf = 0; nf < 4; ++nf) {
                    int col = wn + nf * 16 + (l & 15);
#pragma unroll
                    for (int j = 0; j < 4; ++j) {
                        int row = wm + mf * 16 + (l >> 4) * 4 + j;
                        size_t idx = (size_t)(m0 + row) * C_DIM + col;
                        float v = acc[mf][nf][j] + bias[col] + res[idx];
                        zl[(row & 63) * 129 + col] = locf[idx] + v;
                    }
                }
        }
        __syncthreads();
        {
            int c = t >> 1, mseg = (t & 1) * 32;
            size_t gb = (size_t)c * N_TOK + m0 + half * 64 + mseg;
#pragma unroll
            for (int mm = 0; mm < 32; mm += 4) {
                float4 xv = *(const float4*)(xin + gb + mm);
                float z0 = zl[(mseg + mm + 0) * 129 + c];
                float z1 = zl[(mseg + mm + 1) * 129 + c];
                float z2 = zl[(mseg + mm + 2) * 129 + c];
                float z3 = zl[(mseg + mm + 3) * 129 + c];
                float4 ov;
                ov.x = xv.x / (1.0f + __expf(-z0));
                ov.y = xv.y / (1.0f + __expf(-z1));
                ov.z = xv.z / (1.0f + __expf(-z2));
                ov.w = xv.w / (1.0f + __expf(-z3));
                *(float4*)(outp + gb + mm) = ov;
            }
        }
        __syncthreads();
    }
}

// ------- fused: transpose+LN1 (blocks 0..255) + weight cvt (blocks 256..295) --------
__global__ __launch_bounds__(256) void prep_k(const float* __restrict__ x,
                                              const float* __restrict__ g1, const float* __restrict__ b1,
                                              const float* __restrict__ g2, const float* __restrict__ b2,
                                              float* __restrict__ xt,
                                              short* __restrict__ o1, short* __restrict__ o2,
                                              CvtArgs ca) {
    __shared__ float tile[32][132];
    int t = threadIdx.x;
    if (blockIdx.x >= 256) {
        int bid = blockIdx.x - 256;
#pragma unroll 1
        for (int d = 0; d < 10; ++d) {
            CvtDesc dd = ca.d[d];
            if (dd.pad) {
                for (int i = bid * 256 + t; i < dd.n; i += 40 * 256) {
                    int co = i >> 10, qq = i & 1023;
                    dd.dst[co * 1024 + ((qq & 7) << 7) + (qq >> 3)] = f2b(dd.src[i]);
                }
            } else {
                for (int i = bid * 256 + t; i < dd.n; i += 40 * 256)
                    dd.dst[i] = f2b(dd.src[i]);
            }
        }
        return;
    }
    int n0 = blockIdx.x * 32;
#pragma unroll
    for (int k = 0; k < 16; ++k) {
        int f = t + k * 256;
        int n = f & 31, c = f >> 5;
        tile[n][c] = x[(size_t)c * N_TOK + n0 + n];
    }
    __syncthreads();
    int tk = t >> 3, cb = (t & 7) * 16;
    float v[16];
    float s = 0.f, sq = 0.f;
#pragma unroll
    for (int i = 0; i < 16; ++i) {
        v[i] = tile[tk][cb + i];
        s += v[i]; sq += v[i] * v[i];
    }
    s += __shfl_xor(s, 1);  s += __shfl_xor(s, 2);  s += __shfl_xor(s, 4);
    sq += __shfl_xor(sq, 1); sq += __shfl_xor(sq, 2); sq += __shfl_xor(sq, 4);
    float m = s * (1.0f / 128.0f);
    float var = sq * (1.0f / 128.0f) - m * m;
    float rs = rsqrtf(var + EPSV);
    int tok = n0 + tk;
    float* xp = xt + (size_t)tok * C_DIM + cb;
    *(float4*)(xp)      = make_float4(v[0], v[1], v[2], v[3]);
    *(float4*)(xp + 4)  = make_float4(v[4], v[5], v[6], v[7]);
    *(float4*)(xp + 8)  = make_float4(v[8], v[9], v[10], v[11]);
    *(float4*)(xp + 12) = make_float4(v[12], v[13], v[14], v[15]);
    float hA[16], hB[16];
#pragma unroll
    for (int i = 0; i < 16; ++i) {
        float hn = (v[i] - m) * rs;
        hA[i] = hn * g1[cb + i] + b1[cb + i];
        hB[i] = hn * g2[cb + i] + b2[cb + i];
    }
    uint4 ua0 = {pk2(hA[0], hA[1]), pk2(hA[2], hA[3]), pk2(hA[4], hA[5]), pk2(hA[6], hA[7])};
    uint4 ua1 = {pk2(hA[8], hA[9]), pk2(hA[10], hA[11]), pk2(hA[12], hA[13]), pk2(hA[14], hA[15])};
    uint4 ub0 = {pk2(hB[0], hB[1]), pk2(hB[2], hB[3]), pk2(hB[4], hB[5]), pk2(hB[6], hB[7])};
    uint4 ub1 = {pk2(hB[8], hB[9]), pk2(hB[10], hB[11]), pk2(hB[12], hB[13]), pk2(hB[14], hB[15])};
    *(uint4*)(o1 + (size_t)tok * C_DIM + cb)     = ua0;
    *(uint4*)(o1 + (size_t)tok * C_DIM + cb + 8) = ua1;
    *(uint4*)(o2 + (size_t)tok * C_DIM + cb)     = ub0;
    *(uint4*)(o2 + (size_t)tok * C_DIM + cb + 8) = ub1;
}

// ---------------- qkv GEMMs, branch-paired ----------------
struct MArgs {
    const short* A[2]; const short* W[2];
    void* out[2];
};
__global__ __launch_bounds__(256) void qkv_k(MArgs ga, int M, int N, int K) {
    __shared__ char smem[65536];
    int zi = blockIdx.z;
    f32x4 acc[4][4];
#pragma unroll
    for (int a = 0; a < 4; ++a)
#pragma unroll
        for (int b = 0; b < 4; ++b) acc[a][b] = f32x4{0.f, 0.f, 0.f, 0.f};
    mm128(ga.A[zi], ga.W[zi], K, blockIdx.x * 128, blockIdx.y * 128, threadIdx.x, smem, acc);
    epi_bf16<0>(acc, nullptr, (short*)ga.out[zi], blockIdx.x * 128, blockIdx.y * 128, N, threadIdx.x);
}

// ------- fused: conv reductions w/ inline gather (blocks 0..127) + local attention --
struct CLArgs {
    const short* qkv_g; const short* wk; const short* wv;
    float* kpart; float* vpart;
    const short* qkv_l; short* ob;
};
__global__ __launch_bounds__(256) void convlat_k(CLArgs ga) {
    __shared__ char smem[65536];
    int t = threadIdx.x;
    if (blockIdx.x < 128) {
        int bid = blockIdx.x;
        int m0 = (bid & 7) * 128;
        int zi = bid >> 6;
        int slice = (bid >> 3) & 7;
        const short* Abase = ga.qkv_g + (zi ? 256 : 128);
        const short* W = zi ? ga.wv : ga.wk;
        float* outp = zi ? ga.vpart : ga.kpart;
        short (*As)[8192] = (short(*)[8192])smem;
        short (*Bs)[8192] = (short(*)[8192])(smem + 32768);
        int w = t >> 6, l = t & 63;
        int wm = (w >> 1) * 64, wn = (w & 1) * 64;
        int kbeg = slice * 128;
        int od = slice >> 2, oh = (slice >> 1) & 1, ow = slice & 1;

        f32x4 acc[4][4];
#pragma unroll
        for (int a = 0; a < 4; ++a)
#pragma unroll
            for (int b = 0; b < 4; ++b) acc[a][b] = f32x4{0.f, 0.f, 0.f, 0.f};

        auto STAGE = [&](int buf, int k0) {
#pragma unroll
            for (int c = 0; c < 4; ++c) {
                int g0 = c * 256 + w * 64;
                int g  = g0 + l;
                int row = g >> 3, ss = g & 7;
                int slot = ss ^ (row & 7);
                int nr = m0 + row;
                int n = (2 * (nr >> 8) + od) * 1024 + (2 * ((nr >> 4) & 15) + oh) * 32
                        + 2 * (nr & 15) + ow;
                gload16(Abase + (size_t)n * 384 + (k0 & 127) + slot * 8, &As[buf][g0 * 8]);
                gload16(W + (size_t)row * 1024 + k0 + slot * 8, &Bs[buf][g0 * 8]);
            }
        };

        STAGE(0, kbeg);
        int cur = 0;
        for (int it = 0; it < 2; ++it) {
            if (it == 0) {
                STAGE(1, kbeg + 64);
                asm volatile("s_waitcnt vmcnt(8)" ::: "memory");
            } else {
                asm volatile("s_waitcnt vmcnt(0)" ::: "memory");
            }
            __builtin_amdgcn_s_barrier();
#pragma unroll
            for (int kk = 0; kk < 2; ++kk) {
                short8 af[4], bf[4];
                int sl = kk * 4 + (l >> 4);
#pragma unroll
                for (int mf = 0; mf < 4; ++mf) {
                    int row = wm + mf * 16 + (l & 15);
                    af[mf] = *(const short8*)(&As[cur][row * 64 + (sl ^ (row & 7)) * 8]);
                }
#pragma unroll
                for (int nf = 0; nf < 4; ++nf) {
                    int row = wn + nf * 16 + (l & 15);
                    bf[nf] = *(const short8*)(&Bs[cur][row * 64 + (sl ^ (row & 7)) * 8]);
                }
#pragma unroll
                for (int mf = 0; mf < 4; ++mf)
#pragma unroll
                    for (int nf = 0; nf < 4; ++nf)
                        acc[mf][nf] = __builtin_amdgcn_mfma_f32_16x16x32_bf16(
                            af[mf], bf[nf], acc[mf][nf], 0, 0, 0);
            }
            asm volatile("s_waitcnt lgkmcnt(0)" ::: "memory");
            __builtin_amdgcn_sched_barrier(0);
            __builtin_amdgcn_s_barrier();
            cur ^= 1;
        }
#pragma unroll
        for (int mf = 0; mf < 4; ++mf)
#pragma unroll
            for (int nf = 0; nf < 4; ++nf) {
                int col = wn + nf * 16 + (l & 15);
#pragma unroll
                for (int j = 0; j < 4; ++j) {
                    int row = m0 + wm + mf * 16 + (l >> 4) * 4 + j;
                    outp[(size_t)slice * (NR * C_DIM) + (size_t)row * C_DIM + col] =
                        acc[mf][nf][j];
                }
            }
        return;
    }
    float (*ks)[32][HDIM] = (float(*)[32][HDIM])smem;
    float (*vs)[32][HDIM] = (float(*)[32][HDIM])(smem + 16384);
    int m = t & 31, h = t >> 5, r = blockIdx.x - 128;
    int zd = r >> 6, zh = (r >> 3) & 7, zw = r & 7;
    int pd = m >> 4, ph = (m >> 2) & 3, pw = m & 3;
    int n = (zd * 2 + pd) * 1024 + (zh * 4 + ph) * 32 + (zw * 4 + pw);
    const short* base = ga.qkv_l + (size_t)n * 384 + h * HDIM;
    float q[16], kt[16], vt[16];
    ld16bf(base, q);
    ld16bf(base + 128, kt);
    ld16bf(base + 256, vt);
#pragma unroll
    for (int d = 0; d < 16; ++d) { ks[h][m][d] = kt[d]; vs[h][m][d] = vt[d]; }
    __syncthreads();
    float s[32];
#pragma unroll
    for (int j = 0; j < 32; ++j) {
        float d = 0.f;
#pragma unroll
        for (int dd = 0; dd < 16; ++dd) d += q[dd] * ks[h][j][dd];
        s[j] = __expf(d * QK_SCALE);
    }
    float sum = 0.f;
#pragma unroll
    for (int j = 0; j < 32; ++j) sum += s[j];
    float inv = 1.0f / sum;
    float oo[16] = {};
#pragma unroll
    for (int j = 0; j < 32; ++j) {
        float p = s[j] * inv;
#pragma unroll
        for (int dd = 0; dd < 16; ++dd) oo[dd] += p * vs[h][j][dd];
    }
#pragma unroll
    for (int dd = 0; dd < 16; ++dd) {
        int n2 = h * 4 + (dd >> 2);
        int c2 = (dd & 3) * 32 + m;
        int pd2 = n2 >> 4, ph2 = (n2 >> 2) & 3, pw2 = n2 & 3;
        int nn = (zd * 2 + pd2) * 1024 + (zh * 4 + ph2) * 32 + (zw * 4 + pw2);
        ga.ob[(size_t)nn * C_DIM + c2] = f2b(oo[dd]);
    }
}

// ---- stage 4: local proj+LN (blocks 0..63) + head-LN K/V (blocks 64..127) ----
struct S4Args {
    const short* obuf_l; const short* wproj; const float* pbias; const float* xt;
    float* t1; short* t2; const float* lng; const float* lnb;
    const float* kpart; const float* vpart;
    const float* gk; const float* bk; const float* gv; const float* bv;
    short* kout; short* vout;
};
__global__ __launch_bounds__(256) void s4_k(S4Args a) {
    __shared__ char smem[65536];
    int t = threadIdx.x;
    if (blockIdx.x < 64) {
        f32x4 acc[4][4];
#pragma unroll
        for (int i = 0; i < 4; ++i)
#pragma unroll
            for (int j = 0; j < 4; ++j) acc[i][j] = f32x4{0.f, 0.f, 0.f, 0.f};
        mm128(a.obuf_l, a.wproj, 128, blockIdx.x * 128, 0, t, smem, acc);
        proj_ln_epi(acc, a.pbias, a.xt, a.t1, a.t2, a.lng, a.lnb, blockIdx.x * 128, t, smem);
        return;
    }
    // head-LN path
    float (*vlds)[16][33] = (float(*)[16][33])smem;
    int b = blockIdx.x - 64;          // 0..63
    bool sel = b >= 32;
    int bb2 = sel ? (b - 32) : b;
    int id2 = bb2 * 256 + t;
    const float* part = sel ? a.vpart : a.kpart;
    const float* g    = sel ? a.gv : a.gk;
    const float* bbv  = sel ? a.bv : a.bk;
    int nr = id2 >> 3, h = id2 & 7;
    size_t base = (size_t)nr * C_DIM + h * HDIM;
    float v[16] = {};
#pragma unroll
    for (int p = 0; p < 8; ++p) {
        const float* pp = part + (size_t)p * (NR * C_DIM) + base;
#pragma unroll
        for (int d4 = 0; d4 < 4; ++d4) {
            float4 tv = *(const float4*)(pp + d4 * 4);
            v[d4 * 4 + 0] += tv.x; v[d4 * 4 + 1] += tv.y;
            v[d4 * 4 + 2] += tv.z; v[d4 * 4 + 3] += tv.w;
        }
    }
    float s = 0.f;
#pragma unroll
    for (int i = 0; i < 16; ++i) s += v[i];
    float m = s * (1.0f / 16.0f);
    float sq = 0.f;
#pragma unroll
    for (int i = 0; i < 16; ++i) { float d = v[i] - m; sq += d * d; }
    float rs = rsqrtf(sq * (1.0f / 16.0f) + EPSV);
    if (!sel) {
        short* op = a.kout + (size_t)h * (NR * HDIM) + (size_t)nr * HDIM;
#pragma unroll
        for (int i = 0; i < 16; ++i)
            op[i] = f2b(((v[i] - m) * rs * g[i] + bbv[i]) * QK_L2E);
        return;
    }
    int nr_l = t >> 3;
#pragma unroll
    for (int i = 0; i < 16; ++i)
        vlds[h][i][nr_l] = (v[i] - m) * rs * g[i] + bbv[i];
    __syncthreads();
    int row = t >> 1, half = t & 1;
    int h2 = row >> 4, i2 = row & 15;
    const float* src = &vlds[h2][i2][half * 16];
    uint4 u0 = {pk2(src[0], src[1]), pk2(src[2], src[3]), pk2(src[4], src[5]), pk2(src[6], src[7])};
    uint4 u1 = {pk2(src[8], src[9]), pk2(src[10], src[11]), pk2(src[12], src[13]), pk2(src[14], src[15])};
    short* dst = a.vout + (size_t)h2 * (HDIM * NR) + (size_t)i2 * NR + bb2 * 32 + half * 16;
    *(uint4*)(dst)     = u0;
    *(uint4*)(dst + 8) = u1;
}

// ---------------- global attention v8 (unchanged) ----------------
__global__ __launch_bounds__(512) void gattn_k(const short* __restrict__ qkv,
                                               const short* __restrict__ kb,
                                               const short* __restrict__ vt,
                                               short* __restrict__ ob) {
    __shared__ short plds[8][2048];
    __shared__ float comb[4][64][5];
    int t = threadIdx.x;
    int w = t >> 6, l = t & 63;
    int h = blockIdx.y;
    int lr = l & 15, lq = l >> 4;
    int qw = w & 3, kw = w >> 2;
    int q0 = blockIdx.x * 64 + qw * 16;

    short8 qf = short8{0, 0, 0, 0, 0, 0, 0, 0};
    if (lq < 2)
        qf = *(const short8*)(qkv + (size_t)(q0 + lr) * 384 + h * HDIM + lq * 8);

    const short* kh = kb + (size_t)h * (NR * HDIM);
    const short* vh = vt + (size_t)h * (HDIM * NR);
    short* pw = &plds[w][0];

    const f32x4 zz = {0.f, 0.f, 0.f, 0.f};
    f32x4 oacc = {0.f, 0.f, 0.f, 0.f};
    float rs = 0.f;

    for (int c = 0; c < 4; ++c) {
        int kbase = kw * 512 + c * 128;
        f32x4 s[8];
#pragma unroll
        for (int nf = 0; nf < 8; ++nf) {
            short8 kf = short8{0, 0, 0, 0, 0, 0, 0, 0};
            if (lq < 2)
                kf = *(const short8*)(kh + (size_t)(kbase + nf * 16 + lr) * HDIM + lq * 8);
            s[nf] = __builtin_amdgcn_mfma_f32_16x16x32_bf16(kf, qf, zz, 0, 0, 0);
        }
#pragma unroll
        for (int nf = 0; nf < 8; ++nf) {
            float p0 = exp2f(s[nf][0]);
            float p1 = exp2f(s[nf][1]);
            float p2 = exp2f(s[nf][2]);
            float p3 = exp2f(s[nf][3]);
            rs += (p0 + p1) + (p2 + p3);
            unsigned int u01, u23;
            asm("v_cvt_pk_bf16_f32 %0, %1, %2" : "=v"(u01) : "v"(p0), "v"(p1));
            asm("v_cvt_pk_bf16_f32 %0, %1, %2" : "=v"(u23) : "v"(p2), "v"(p3));
            int k0 = nf * 16 + lq * 4;
            int sw = (lr & 7) << 3;
            *(unsigned int*)&pw[lr * 128 + (k0 ^ sw)]       = u01;
            *(unsigned int*)&pw[lr * 128 + ((k0 + 2) ^ sw)] = u23;
        }
#pragma unroll
        for (int ks = 0; ks < 4; ++ks) {
            short8 pf = *(const short8*)&pw[(lr * 128 + ks * 32 + lq * 8) ^ ((lr & 7) << 3)];
            short8 vf = *(const short8*)(vh + (size_t)lr * NR + kbase + ks * 32 + lq * 8);
            oacc = __builtin_amdgcn_mfma_f32_16x16x32_bf16(pf, vf, oacc, 0, 0, 0);
        }
    }
    rs += __shfl_xor(rs, 16);
    rs += __shfl_xor(rs, 32);
    if (w >= 4) {
        comb[w - 4][l][0] = oacc[0];
        comb[w - 4][l][1] = oacc[1];
        comb[w - 4][l][2] = oacc[2];
        comb[w - 4][l][3] = oacc[3];
        comb[w - 4][l][4] = rs;
    }
    __syncthreads();
    if (w < 4) {
        oacc[0] += comb[w][l][0];
        oacc[1] += comb[w][l][1];
        oacc[2] += comb[w][l][2];
        oacc[3] += comb[w][l][3];
        rs += comb[w][l][4];
        float r0 = __shfl(rs, lq * 4 + 0);
        float r1 = __shfl(rs, lq * 4 + 1);
        float r2 = __shfl(rs, lq * 4 + 2);
        float r3 = __shfl(rs, lq * 4 + 3);
        size_t base_o = (size_t)(q0 + lq * 4) * C_DIM + h * HDIM + lr;
        ob[base_o]             = f2b(oacc[0] / r0);
        ob[base_o + C_DIM]     = f2b(oacc[1] / r1);
        ob[base_o + 2 * C_DIM] = f2b(oacc[2] / r2);
        ob[base_o + 3 * C_DIM] = f2b(oacc[3] / r3);
    }
}

// ---- stage 6: global proj+LN (blocks 0..63) + local fc1 gelu (blocks 64..319) ----
struct S6Args {
    const short* obuf_g; const short* wproj; const float* pbias; const float* xt;
    float* t1; short* t2; const float* lng; const float* lnb;
    const short* t2l; const short* wfc1; const float* f1bias; short* h1;
};
__global__ __launch_bounds__(256) void s6_k(S6Args a) {
    __shared__ char smem[65536];
    int t = threadIdx.x;
    f32x4 acc[4][4];
#pragma unroll
    for (int i = 0; i < 4; ++i)
#pragma unroll
        for (int j = 0; j < 4; ++j) acc[i][j] = f32x4{0.f, 0.f, 0.f, 0.f};
    if (blockIdx.x < 64) {
        mm128(a.obuf_g, a.wproj, 128, blockIdx.x * 128, 0, t, smem, acc);
        proj_ln_epi(acc, a.pbias, a.xt, a.t1, a.t2, a.lng, a.lnb, blockIdx.x * 128, t, smem);
    } else {
        int bid = blockIdx.x - 64;
        int m0 = (bid & 63) * 128, n0 = (bid >> 6) * 128;
        mm128(a.t2l, a.wfc1, 128, m0, n0, t, smem, acc);
        epi_bf16<1>(acc, a.f1bias, a.h1, m0, n0, 512, t);
    }
}

// ---- stage 7: global fc1 gelu (blocks 0..255) + local fc2 residual (blocks 256..319) ----
struct S7Args {
    const short* t2g; const short* wfc1; const float* f1bias; short* h1g;
    const short* h1l; const short* wfc2; const float* f2bias; const float* t1l; float* locfin;
};
__global__ __launch_bounds__(256) void s7_k(S7Args a) {
    __shared__ char smem[65536];
    int t = threadIdx.x;
    f32x4 acc[4][4];
#pragma unroll
    for (int i = 0; i < 4; ++i)
#pragma unroll
        for (int j = 0; j < 4; ++j) acc[i][j] = f32x4{0.f, 0.f, 0.f, 0.f};
    if (blockIdx.x < 256) {
        int m0 = (blockIdx.x & 63) * 128, n0 = (blockIdx.x >> 6) * 128;
        mm128(a.t2g, a.wfc1, 128, m0, n0, t, smem, acc);
        epi_bf16<1>(acc, a.f1bias, a.h1g, m0, n0, 512, t);
    } else {
        int m0 = (blockIdx.x - 256) * 128;
        mm128(a.h1l, a.wfc2, 512, m0, 0, t, smem, acc);
        epi_res(acc, a.f2bias, a.t1l, a.locfin, m0, 128, t);
    }
}

// ---- stage 8: global fc2 + residual + gate fused -> out (C,N) ----
struct S8Args {
    const short* h1g; const short* wfc2; const float* f2bias; const float* t1g;
    const float* locfin; const float* xin; float* outp;
};
__global__ __launch_bounds__(256) void s8_k(S8Args a) {
    __shared__ char smem[65536];
    int t = threadIdx.x;
    f32x4 acc[4][4];
#pragma unroll
    for (int i = 0; i < 4; ++i)
#pragma unroll
        for (int j = 0; j < 4; ++j) acc[i][j] = f32x4{0.f, 0.f, 0.f, 0.f};
    int m0 = blockIdx.x * 128;
    mm128(a.h1g, a.wfc2, 512, m0, 0, t, smem, acc);
    gate_epi(acc, a.f2bias, a.t1g, a.locfin, a.xin, a.outp, m0, t, smem);
}

extern "C" void kernel_launch(void* const* d_in, const int* in_sizes, int n_in,
                              void* d_out, int out_size, void* d_ws, size_t ws_size,
                              hipStream_t stream) {
    const float* x        = (const float*)d_in[0];
    const float* l_n1_g   = (const float*)d_in[1];
    const float* l_n1_b   = (const float*)d_in[2];
    const float* l_qkv_w  = (const float*)d_in[3];
    const float* l_proj_w = (const float*)d_in[4];
    const float* l_proj_b = (const float*)d_in[5];
    const float* l_n2_g   = (const float*)d_in[6];
    const float* l_n2_b   = (const float*)d_in[7];
    const float* l_fc1_w  = (const float*)d_in[8];
    const float* l_fc1_b  = (const float*)d_in[9];
    const float* l_fc2_w  = (const float*)d_in[10];
    const float* l_fc2_b  = (const float*)d_in[11];
    const float* g_n1_g   = (const float*)d_in[12];
    const float* g_n1_b   = (const float*)d_in[13];
    const float* g_qkv_w  = (const float*)d_in[14];
    const float* g_proj_w = (const float*)d_in[15];
    const float* g_proj_b = (const float*)d_in[16];
    const float* g_n2_g   = (const float*)d_in[17];
    const float* g_n2_b   = (const float*)d_in[18];
    const float* g_fc1_w  = (const float*)d_in[19];
    const float* g_fc1_b  = (const float*)d_in[20];
    const float* g_fc2_w  = (const float*)d_in[21];
    const float* g_fc2_b  = (const float*)d_in[22];
    const float* g_ke_w   = (const float*)d_in[23];
    const float* g_ve_w   = (const float*)d_in[24];
    const float* g_nk_g   = (const float*)d_in[25];
    const float* g_nk_b   = (const float*)d_in[26];
    const float* g_nv_g   = (const float*)d_in[27];
    const float* g_nv_b   = (const float*)d_in[28];
    float* out = (float*)d_out;

    char* base = (char*)d_ws;
    float* xt     = (float*)(base);                        // 0-4 MB
    float* t1_l   = (float*)(base + (4ull  << 20));        // 4-8 MB
    float* t1_g   = (float*)(base + (8ull  << 20));        // 8-12 MB
    short* yA16   = (short*)(base + (12ull << 20));        // 12-14 (later t2_l)
    short* yG16   = (short*)(base + (14ull << 20));        // 14-16 (later t2_g)
    short* t2_l   = yA16;
    short* t2_g   = yG16;
    short* obuf_l = (short*)(base + (16ull << 20));        // 16-18
    short* obuf_g = (short*)(base + (18ull << 20));        // 18-20
    float* locfin = (float*)(base + (16ull << 20));        // 16-20 (after both obufs consumed)
    short* qkv_l  = (short*)(base + (20ull << 20));        // 20-26
    short* qkv_g  = (short*)(base + (26ull << 20));        // 26-32
    float* kpart  = (float*)(base + (32ull << 20));        // 32-36 (consumed stage 4)
    float* vpart  = (float*)(base + (36ull << 20));        // 36-40 (consumed stage 4)
    short* h1_l   = (short*)(base + (32ull << 20));        // 32-40 (written stage 6)
    short* h1_g   = (short*)(base + (40ull << 20));        // 40-48
    short* kb16   = (short*)(base + (48ull << 20));        // [8][1024][16]
    short* vt16   = (short*)(base + (48ull << 20) + (512ull << 10)); // [8][16][1024]
    short* wts    = (short*)(base + (49ull << 20));        // ~1.3 MB

    const int L_QKV = 0,      L_PROJ = 49152, L_FC1 = 65536,  L_FC2 = 131072;
    const int G_QKV = 196608, G_PROJ = 245760, G_FC1 = 262144, G_FC2 = 327680;
    const int G_KE  = 393216, G_VE   = 524288;

    CvtArgs ca;
    ca.d[0] = {l_qkv_w,  wts + L_QKV,  49152, 0};
    ca.d[1] = {l_proj_w, wts + L_PROJ, 16384, 0};
    ca.d[2] = {l_fc1_w,  wts + L_FC1,  65536, 0};
    ca.d[3] = {l_fc2_w,  wts + L_FC2,  65536, 0};
    ca.d[4] = {g_qkv_w,  wts + G_QKV,  49152, 0};
    ca.d[5] = {g_proj_w, wts + G_PROJ, 16384, 0};
    ca.d[6] = {g_fc1_w,  wts + G_FC1,  65536, 0};
    ca.d[7] = {g_fc2_w,  wts + G_FC2,  65536, 0};
    ca.d[8] = {g_ke_w,   wts + G_KE,  131072, 1};
    ca.d[9] = {g_ve_w,   wts + G_VE,  131072, 1};

    // 1: transpose + LN1 + weight cvt
    prep_k<<<296, 256, 0, stream>>>(x, l_n1_g, l_n1_b, g_n1_g, g_n1_b, xt, yA16, yG16, ca);

    // 2: both qkv GEMMs
    MArgs a_qkv = {{yA16, yG16}, {wts + L_QKV, wts + G_QKV}, {qkv_l, qkv_g}};
    qkv_k<<<dim3(64, 3, 2), 256, 0, stream>>>(a_qkv, N_TOK, 384, 128);

    // 3: conv reductions (inline gather, split-K x8) + local attention
    CLArgs cla = {qkv_g, wts + G_KE, wts + G_VE, kpart, vpart, qkv_l, obuf_l};
    convlat_k<<<384, 256, 0, stream>>>(cla);

    // 4: local proj + LN2 (fused) || head-LN K/V
    S4Args a4 = {obuf_l, wts + L_PROJ, l_proj_b, xt, t1_l, t2_l, l_n2_g, l_n2_b,
                 kpart, vpart, g_nk_g, g_nk_b, g_nv_g, g_nv_b, kb16, vt16};
    s4_k<<<128, 256, 0, stream>>>(a4);

    // 5: global attention
    gattn_k<<<dim3(128, 8), 512, 0, stream>>>(qkv_g, kb16, vt16, obuf_g);

    // 6: global proj + LN2 (fused) || local fc1 (gelu)
    S6Args a6 = {obuf_g, wts + G_PROJ, g_proj_b, xt, t1_g, t2_g, g_n2_g, g_n2_b,
                 t2_l, wts + L_FC1, l_fc1_b, h1_l};
    s6_k<<<320, 256, 0, stream>>>(a6);

    // 7: global fc1 (gelu) || local fc2 (+res -> locfin)
    S7Args a7 = {t2_g, wts + G_FC1, g_fc1_b, h1_g,
                 h1_l, wts + L_FC2, l_fc2_b, t1_l, locfin};
    s7_k<<<320, 256, 0, stream>>>(a7);

    // 8: global fc2 + residual + gate -> out (C,N)
    S8Args a8 = {h1_g, wts + G_FC2, g_fc2_b, t1_g, locfin, x, out};
    s8_k<<<64, 256, 0, stream>>>(a8);
}

// Round 13
// 137.766 us; speedup vs baseline: 1.2690x; 1.2690x over previous
//
#include <hip/hip_runtime.h>
#include <math.h>

#define N_TOK 8192
#define C_DIM 128
#define NHD   8
#define HDIM  16
#define NR    1024
#define EPSV  1e-5f
#define QK_SCALE 0.25f
#define QK_L2E  0.36067376f   /* 0.25 * log2(e) */

typedef __attribute__((ext_vector_type(8))) short short8;
typedef __attribute__((ext_vector_type(4))) float f32x4;

__device__ __forceinline__ float gelu_f(float v) {
    float u = 0.7978845608f * (v + 0.044715f * v * v * v);
    float e = exp2f(2.885390082f * u);
    return v * (e / (e + 1.0f));
}
__device__ __forceinline__ float uaf(unsigned int u) {
    union { unsigned int u; float f; } x; x.u = u; return x.f;
}
__device__ __forceinline__ short f2b(float v) {
    union { float f; unsigned int u; } x; x.f = v;
    unsigned int r = x.u + 0x7fffu + ((x.u >> 16) & 1u);
    return (short)(r >> 16);
}
__device__ __forceinline__ unsigned int pk2(float a, float b) {
    return (unsigned int)(unsigned short)f2b(a) | ((unsigned int)(unsigned short)f2b(b) << 16);
}
__device__ __forceinline__ void ld16bf(const short* p, float* d) {
    uint4 a = *(const uint4*)p;
    uint4 b = *(const uint4*)(p + 8);
    d[0]  = uaf(a.x << 16); d[1]  = uaf(a.x & 0xffff0000u);
    d[2]  = uaf(a.y << 16); d[3]  = uaf(a.y & 0xffff0000u);
    d[4]  = uaf(a.z << 16); d[5]  = uaf(a.z & 0xffff0000u);
    d[6]  = uaf(a.w << 16); d[7]  = uaf(a.w & 0xffff0000u);
    d[8]  = uaf(b.x << 16); d[9]  = uaf(b.x & 0xffff0000u);
    d[10] = uaf(b.y << 16); d[11] = uaf(b.y & 0xffff0000u);
    d[12] = uaf(b.z << 16); d[13] = uaf(b.z & 0xffff0000u);
    d[14] = uaf(b.w << 16); d[15] = uaf(b.w & 0xffff0000u);
}

// async global->LDS, 16B per lane; LDS dest = wave-uniform base + lane*16
__device__ __forceinline__ void gload16(const void* g, void* l) {
    __builtin_amdgcn_global_load_lds(
        (const __attribute__((address_space(1))) unsigned int*)g,
        (__attribute__((address_space(3))) unsigned int*)l, 16, 0, 0);
}

struct CvtDesc { const float* src; short* dst; int n; int pad; };
struct CvtArgs { CvtDesc d[10]; };

// ------- fused: transpose+LN1 (blocks 0..255) + weight cvt (blocks 256..295) --------
__global__ __launch_bounds__(256) void prep_k(const float* __restrict__ x,
                                              const float* __restrict__ g1, const float* __restrict__ b1,
                                              const float* __restrict__ g2, const float* __restrict__ b2,
                                              float* __restrict__ xt,
                                              short* __restrict__ o1, short* __restrict__ o2,
                                              CvtArgs ca) {
    __shared__ float tile[32][132];
    int t = threadIdx.x;
    if (blockIdx.x >= 256) {
        int bid = blockIdx.x - 256;   // 0..39
#pragma unroll 1
        for (int d = 0; d < 10; ++d) {
            CvtDesc dd = ca.d[d];
            if (dd.pad) {
                for (int i = bid * 256 + t; i < dd.n; i += 40 * 256) {
                    int co = i >> 10, qq = i & 1023;
                    dd.dst[co * 1024 + ((qq & 7) << 7) + (qq >> 3)] = f2b(dd.src[i]);
                }
            } else {
                for (int i = bid * 256 + t; i < dd.n; i += 40 * 256)
                    dd.dst[i] = f2b(dd.src[i]);
            }
        }
        return;
    }
    int n0 = blockIdx.x * 32;
#pragma unroll
    for (int k = 0; k < 16; ++k) {
        int f = t + k * 256;
        int n = f & 31, c = f >> 5;
        tile[n][c] = x[(size_t)c * N_TOK + n0 + n];
    }
    __syncthreads();
    int tk = t >> 3, cb = (t & 7) * 16;
    float v[16];
    float s = 0.f, sq = 0.f;
#pragma unroll
    for (int i = 0; i < 16; ++i) {
        v[i] = tile[tk][cb + i];
        s += v[i]; sq += v[i] * v[i];
    }
    s += __shfl_xor(s, 1);  s += __shfl_xor(s, 2);  s += __shfl_xor(s, 4);
    sq += __shfl_xor(sq, 1); sq += __shfl_xor(sq, 2); sq += __shfl_xor(sq, 4);
    float m = s * (1.0f / 128.0f);
    float var = sq * (1.0f / 128.0f) - m * m;
    float rs = rsqrtf(var + EPSV);
    int tok = n0 + tk;
    float* xp = xt + (size_t)tok * C_DIM + cb;
    *(float4*)(xp)      = make_float4(v[0], v[1], v[2], v[3]);
    *(float4*)(xp + 4)  = make_float4(v[4], v[5], v[6], v[7]);
    *(float4*)(xp + 8)  = make_float4(v[8], v[9], v[10], v[11]);
    *(float4*)(xp + 12) = make_float4(v[12], v[13], v[14], v[15]);
    float hA[16], hB[16];
#pragma unroll
    for (int i = 0; i < 16; ++i) {
        float hn = (v[i] - m) * rs;
        hA[i] = hn * g1[cb + i] + b1[cb + i];
        hB[i] = hn * g2[cb + i] + b2[cb + i];
    }
    uint4 ua0 = {pk2(hA[0], hA[1]), pk2(hA[2], hA[3]), pk2(hA[4], hA[5]), pk2(hA[6], hA[7])};
    uint4 ua1 = {pk2(hA[8], hA[9]), pk2(hA[10], hA[11]), pk2(hA[12], hA[13]), pk2(hA[14], hA[15])};
    uint4 ub0 = {pk2(hB[0], hB[1]), pk2(hB[2], hB[3]), pk2(hB[4], hB[5]), pk2(hB[6], hB[7])};
    uint4 ub1 = {pk2(hB[8], hB[9]), pk2(hB[10], hB[11]), pk2(hB[12], hB[13]), pk2(hB[14], hB[15])};
    *(uint4*)(o1 + (size_t)tok * C_DIM + cb)     = ua0;
    *(uint4*)(o1 + (size_t)tok * C_DIM + cb + 8) = ua1;
    *(uint4*)(o2 + (size_t)tok * C_DIM + cb)     = ub0;
    *(uint4*)(o2 + (size_t)tok * C_DIM + cb + 8) = ub1;
}

// ---------------- second LN, paired across branches ----------------
__global__ __launch_bounds__(256) void ln2_pair_k(const float* __restrict__ in0,
                                                  const float* __restrict__ g0, const float* __restrict__ b0,
                                                  short* __restrict__ o0,
                                                  const float* __restrict__ in1,
                                                  const float* __restrict__ g1, const float* __restrict__ b1,
                                                  short* __restrict__ o1) {
    int blk = blockIdx.x;
    bool sel = blk >= 2048;
    blk &= 2047;
    const float* in = sel ? in1 : in0;
    const float* g  = sel ? g1 : g0;
    const float* b  = sel ? b1 : b0;
    short* o        = sel ? o1 : o0;
    int lane = threadIdx.x & 63;
    int n = blk * 4 + (threadIdx.x >> 6);
    float v0 = in[(size_t)n * C_DIM + lane];
    float v1 = in[(size_t)n * C_DIM + 64 + lane];
    float s = v0 + v1, sq = v0 * v0 + v1 * v1;
#pragma unroll
    for (int off = 32; off >= 1; off >>= 1) {
        s += __shfl_xor(s, off);
        sq += __shfl_xor(sq, off);
    }
    float m = s * (1.0f / 128.0f);
    float var = sq * (1.0f / 128.0f) - m * m;
    float rs = rsqrtf(var + EPSV);
    o[(size_t)n * C_DIM + lane]      = f2b((v0 - m) * rs * g[lane] + b[lane]);
    o[(size_t)n * C_DIM + 64 + lane] = f2b((v1 - m) * rs * g[lane + 64] + b[lane + 64]);
}

// ---------------- bf16 MFMA GEMM, async-staged 2-phase pipeline ----------------
// EPI: 0 bf16 out; 1 f32 = acc+bias+res; 2 bf16 = gelu(acc+bias)
struct MArgs {
    const short* A[2]; const short* W[2];
    const float* bias[2]; const float* res[2];
    void* out[2];
};
template <int EPI>
__global__ __launch_bounds__(256) void mgemm_k(MArgs ga, int M, int N, int K) {
    int zi = blockIdx.z;
    const short* A = ga.A[zi];
    const short* W = ga.W[zi];
    __shared__ short As[2][128 * 64];
    __shared__ short Bs[2][128 * 64];
    int t = threadIdx.x;
    int w = t >> 6, l = t & 63;
    int m0 = blockIdx.x * 128, n0 = blockIdx.y * 128;
    int wm = (w >> 1) * 64, wn = (w & 1) * 64;

    f32x4 acc[4][4];
#pragma unroll
    for (int a = 0; a < 4; ++a)
#pragma unroll
        for (int b = 0; b < 4; ++b) acc[a][b] = f32x4{0.f, 0.f, 0.f, 0.f};

    // pre-swizzled-source staging: LDS linear per wave, global addr carries the XOR
    auto STAGE = [&](int buf, int k0) {
#pragma unroll
        for (int c = 0; c < 4; ++c) {
            int g0 = c * 256 + w * 64;
            int g  = g0 + l;
            int row = g >> 3, ss = g & 7;
            int slot = ss ^ (row & 7);
            gload16(A + (size_t)(m0 + row) * K + k0 + slot * 8, &As[buf][g0 * 8]);
            gload16(W + (size_t)(n0 + row) * K + k0 + slot * 8, &Bs[buf][g0 * 8]);
        }
    };

    int NT = K >> 6;
    STAGE(0, 0);
    int cur = 0;
    for (int it = 0; it < NT; ++it) {
        if (it + 1 < NT) {
            STAGE(cur ^ 1, (it + 1) << 6);
            asm volatile("s_waitcnt vmcnt(8)" ::: "memory");   // current tile landed
        } else {
            asm volatile("s_waitcnt vmcnt(0)" ::: "memory");
        }
        __builtin_amdgcn_s_barrier();
#pragma unroll
        for (int kk = 0; kk < 2; ++kk) {
            short8 af[4], bf[4];
            int sl = kk * 4 + (l >> 4);
#pragma unroll
            for (int mf = 0; mf < 4; ++mf) {
                int row = wm + mf * 16 + (l & 15);
                af[mf] = *(const short8*)(&As[cur][row * 64 + (sl ^ (row & 7)) * 8]);
            }
#pragma unroll
            for (int nf = 0; nf < 4; ++nf) {
                int row = wn + nf * 16 + (l & 15);
                bf[nf] = *(const short8*)(&Bs[cur][row * 64 + (sl ^ (row & 7)) * 8]);
            }
#pragma unroll
            for (int mf = 0; mf < 4; ++mf)
#pragma unroll
                for (int nf = 0; nf < 4; ++nf)
                    acc[mf][nf] = __builtin_amdgcn_mfma_f32_16x16x32_bf16(
                        af[mf], bf[nf], acc[mf][nf], 0, 0, 0);
        }
        asm volatile("s_waitcnt lgkmcnt(0)" ::: "memory");
        __builtin_amdgcn_sched_barrier(0);
        __builtin_amdgcn_s_barrier();
        cur ^= 1;
    }

    // C/D layout: col = lane&15, row = (lane>>4)*4 + reg
#pragma unroll
    for (int mf = 0; mf < 4; ++mf) {
#pragma unroll
        for (int nf = 0; nf < 4; ++nf) {
            int col = n0 + wn + nf * 16 + (l & 15);
#pragma unroll
            for (int j = 0; j < 4; ++j) {
                int row = m0 + wm + mf * 16 + (l >> 4) * 4 + j;
                float v = acc[mf][nf][j];
                if (EPI == 0) {
                    ((short*)ga.out[zi])[(size_t)row * N + col] = f2b(v);
                } else if (EPI == 1) {
                    v += ga.bias[zi][col] + ga.res[zi][(size_t)row * N + col];
                    ((float*)ga.out[zi])[(size_t)row * N + col] = v;
                } else if (EPI == 2) {
                    v = gelu_f(v + ga.bias[zi][col]);
                    ((short*)ga.out[zi])[(size_t)row * N + col] = f2b(v);
                }
            }
        }
    }
}

// ------- fused: conv reductions w/ inline gather (blocks 0..127) + local attention --
struct CLArgs {
    const short* qkv_g; const short* wk; const short* wv;
    float* kpart; float* vpart;
    const short* qkv_l; short* ob;
};
__global__ __launch_bounds__(256) void convlat_k(CLArgs ga) {
    __shared__ char smem[65536];
    int t = threadIdx.x;
    if (blockIdx.x < 128) {
        int bid = blockIdx.x;
        int m0 = (bid & 7) * 128;
        int zi = bid >> 6;
        int slice = (bid >> 3) & 7;
        const short* Abase = ga.qkv_g + (zi ? 256 : 128);
        const short* W = zi ? ga.wv : ga.wk;
        float* outp = zi ? ga.vpart : ga.kpart;
        short (*As)[8192] = (short(*)[8192])smem;
        short (*Bs)[8192] = (short(*)[8192])(smem + 32768);
        int w = t >> 6, l = t & 63;
        int wm = (w >> 1) * 64, wn = (w & 1) * 64;
        int kbeg = slice * 128;
        int od = slice >> 2, oh = (slice >> 1) & 1, ow = slice & 1;

        f32x4 acc[4][4];
#pragma unroll
        for (int a = 0; a < 4; ++a)
#pragma unroll
            for (int b = 0; b < 4; ++b) acc[a][b] = f32x4{0.f, 0.f, 0.f, 0.f};

        auto STAGE = [&](int buf, int k0) {
#pragma unroll
            for (int c = 0; c < 4; ++c) {
                int g0 = c * 256 + w * 64;
                int g  = g0 + l;
                int row = g >> 3, ss = g & 7;
                int slot = ss ^ (row & 7);
                int nr = m0 + row;
                int n = (2 * (nr >> 8) + od) * 1024 + (2 * ((nr >> 4) & 15) + oh) * 32
                        + 2 * (nr & 15) + ow;
                gload16(Abase + (size_t)n * 384 + (k0 & 127) + slot * 8, &As[buf][g0 * 8]);
                gload16(W + (size_t)row * 1024 + k0 + slot * 8, &Bs[buf][g0 * 8]);
            }
        };

        STAGE(0, kbeg);
        int cur = 0;
        for (int it = 0; it < 2; ++it) {
            if (it == 0) {
                STAGE(1, kbeg + 64);
                asm volatile("s_waitcnt vmcnt(8)" ::: "memory");
            } else {
                asm volatile("s_waitcnt vmcnt(0)" ::: "memory");
            }
            __builtin_amdgcn_s_barrier();
#pragma unroll
            for (int kk = 0; kk < 2; ++kk) {
                short8 af[4], bf[4];
                int sl = kk * 4 + (l >> 4);
#pragma unroll
                for (int mf = 0; mf < 4; ++mf) {
                    int row = wm + mf * 16 + (l & 15);
                    af[mf] = *(const short8*)(&As[cur][row * 64 + (sl ^ (row & 7)) * 8]);
                }
#pragma unroll
                for (int nf = 0; nf < 4; ++nf) {
                    int row = wn + nf * 16 + (l & 15);
                    bf[nf] = *(const short8*)(&Bs[cur][row * 64 + (sl ^ (row & 7)) * 8]);
                }
#pragma unroll
                for (int mf = 0; mf < 4; ++mf)
#pragma unroll
                    for (int nf = 0; nf < 4; ++nf)
                        acc[mf][nf] = __builtin_amdgcn_mfma_f32_16x16x32_bf16(
                            af[mf], bf[nf], acc[mf][nf], 0, 0, 0);
            }
            asm volatile("s_waitcnt lgkmcnt(0)" ::: "memory");
            __builtin_amdgcn_sched_barrier(0);
            __builtin_amdgcn_s_barrier();
            cur ^= 1;
        }
#pragma unroll
        for (int mf = 0; mf < 4; ++mf)
#pragma unroll
            for (int nf = 0; nf < 4; ++nf) {
                int col = wn + nf * 16 + (l & 15);
#pragma unroll
                for (int j = 0; j < 4; ++j) {
                    int row = m0 + wm + mf * 16 + (l >> 4) * 4 + j;
                    outp[(size_t)slice * (NR * C_DIM) + (size_t)row * C_DIM + col] =
                        acc[mf][nf][j];
                }
            }
        return;
    }
    float (*ks)[32][HDIM] = (float(*)[32][HDIM])smem;
    float (*vs)[32][HDIM] = (float(*)[32][HDIM])(smem + 16384);
    int m = t & 31, h = t >> 5, r = blockIdx.x - 128;
    int zd = r >> 6, zh = (r >> 3) & 7, zw = r & 7;
    int pd = m >> 4, ph = (m >> 2) & 3, pw = m & 3;
    int n = (zd * 2 + pd) * 1024 + (zh * 4 + ph) * 32 + (zw * 4 + pw);
    const short* base = ga.qkv_l + (size_t)n * 384 + h * HDIM;
    float q[16], kt[16], vt[16];
    ld16bf(base, q);
    ld16bf(base + 128, kt);
    ld16bf(base + 256, vt);
#pragma unroll
    for (int d = 0; d < 16; ++d) { ks[h][m][d] = kt[d]; vs[h][m][d] = vt[d]; }
    __syncthreads();
    float s[32];
#pragma unroll
    for (int j = 0; j < 32; ++j) {
        float d = 0.f;
#pragma unroll
        for (int dd = 0; dd < 16; ++dd) d += q[dd] * ks[h][j][dd];
        s[j] = __expf(d * QK_SCALE);
    }
    float sum = 0.f;
#pragma unroll
    for (int j = 0; j < 32; ++j) sum += s[j];
    float inv = 1.0f / sum;
    float oo[16] = {};
#pragma unroll
    for (int j = 0; j < 32; ++j) {
        float p = s[j] * inv;
#pragma unroll
        for (int dd = 0; dd < 16; ++dd) oo[dd] += p * vs[h][j][dd];
    }
#pragma unroll
    for (int dd = 0; dd < 16; ++dd) {
        int n2 = h * 4 + (dd >> 2);
        int c2 = (dd & 3) * 32 + m;
        int pd2 = n2 >> 4, ph2 = (n2 >> 2) & 3, pw2 = n2 & 3;
        int nn = (zd * 2 + pd2) * 1024 + (zh * 4 + ph2) * 32 + (zw * 4 + pw2);
        ga.ob[(size_t)nn * C_DIM + c2] = f2b(oo[dd]);
    }
}

// ------- sum 8 split-K partials + per-head LN; K -> bf16 *0.25*log2e, V -> bf16^T ---
// blocks 0..31: K (direct contiguous stores). blocks 32..63: V (LDS-transposed stores).
__global__ __launch_bounds__(256) void ln_head_sum_k(const float* __restrict__ kpart,
                                                     const float* __restrict__ vpart,
                                                     const float* __restrict__ gk, const float* __restrict__ bk,
                                                     const float* __restrict__ gv, const float* __restrict__ bv,
                                                     short* __restrict__ kout, short* __restrict__ vout) {
    __shared__ float vlds[8][16][33];
    int t = threadIdx.x;
    bool sel = blockIdx.x >= 32;
    int b = sel ? (blockIdx.x - 32) : blockIdx.x;
    int id2 = b * 256 + t;
    const float* part = sel ? vpart : kpart;
    const float* g    = sel ? gv : gk;
    const float* bb   = sel ? bv : bk;
    int nr = id2 >> 3, h = id2 & 7;
    size_t base = (size_t)nr * C_DIM + h * HDIM;
    float v[16] = {};
#pragma unroll
    for (int p = 0; p < 8; ++p) {
        const float* pp = part + (size_t)p * (NR * C_DIM) + base;
#pragma unroll
        for (int d4 = 0; d4 < 4; ++d4) {
            float4 tv = *(const float4*)(pp + d4 * 4);
            v[d4 * 4 + 0] += tv.x; v[d4 * 4 + 1] += tv.y;
            v[d4 * 4 + 2] += tv.z; v[d4 * 4 + 3] += tv.w;
        }
    }
    float s = 0.f;
#pragma unroll
    for (int i = 0; i < 16; ++i) s += v[i];
    float m = s * (1.0f / 16.0f);
    float sq = 0.f;
#pragma unroll
    for (int i = 0; i < 16; ++i) { float d = v[i] - m; sq += d * d; }
    float rs = rsqrtf(sq * (1.0f / 16.0f) + EPSV);
    if (!sel) {
        short* op = kout + (size_t)h * (NR * HDIM) + (size_t)nr * HDIM;
#pragma unroll
        for (int i = 0; i < 16; ++i)
            op[i] = f2b(((v[i] - m) * rs * g[i] + bb[i]) * QK_L2E);
        return;
    }
    int nr_l = t >> 3;               // 0..31  (h = t&7)
#pragma unroll
    for (int i = 0; i < 16; ++i)
        vlds[h][i][nr_l] = (v[i] - m) * rs * g[i] + bb[i];
    __syncthreads();
    int row = t >> 1, half = t & 1;  // 128 rows = (h2,i2); 2 threads/row
    int h2 = row >> 4, i2 = row & 15;
    const float* src = &vlds[h2][i2][half * 16];
    uint4 u0 = {pk2(src[0], src[1]), pk2(src[2], src[3]), pk2(src[4], src[5]), pk2(src[6], src[7])};
    uint4 u1 = {pk2(src[8], src[9]), pk2(src[10], src[11]), pk2(src[12], src[13]), pk2(src[14], src[15])};
    short* dst = vout + (size_t)h2 * (HDIM * NR) + (size_t)i2 * NR + b * 32 + half * 16;
    *(uint4*)(dst)     = u0;
    *(uint4*)(dst + 8) = u1;
}

// ---------------- global attention v8: 8 waves, split-K wave pairs ----------------
__global__ __launch_bounds__(512) void gattn_k(const short* __restrict__ qkv,
                                               const short* __restrict__ kb,   // [8][1024][16] *0.25*log2e
                                               const short* __restrict__ vt,   // [8][16][1024]
                                               short* __restrict__ ob) {
    __shared__ short plds[8][2048];
    __shared__ float comb[4][64][5];
    int t = threadIdx.x;
    int w = t >> 6, l = t & 63;
    int h = blockIdx.y;
    int lr = l & 15, lq = l >> 4;
    int qw = w & 3, kw = w >> 2;
    int q0 = blockIdx.x * 64 + qw * 16;

    short8 qf = short8{0, 0, 0, 0, 0, 0, 0, 0};
    if (lq < 2)
        qf = *(const short8*)(qkv + (size_t)(q0 + lr) * 384 + h * HDIM + lq * 8);

    const short* kh = kb + (size_t)h * (NR * HDIM);
    const short* vh = vt + (size_t)h * (HDIM * NR);
    short* pw = &plds[w][0];

    const f32x4 zz = {0.f, 0.f, 0.f, 0.f};
    f32x4 oacc = {0.f, 0.f, 0.f, 0.f};
    float rs = 0.f;

    for (int c = 0; c < 4; ++c) {
        int kbase = kw * 512 + c * 128;
        f32x4 s[8];
#pragma unroll
        for (int nf = 0; nf < 8; ++nf) {
            short8 kf = short8{0, 0, 0, 0, 0, 0, 0, 0};
            if (lq < 2)
                kf = *(const short8*)(kh + (size_t)(kbase + nf * 16 + lr) * HDIM + lq * 8);
            s[nf] = __builtin_amdgcn_mfma_f32_16x16x32_bf16(kf, qf, zz, 0, 0, 0);
        }
#pragma unroll
        for (int nf = 0; nf < 8; ++nf) {
            float p0 = exp2f(s[nf][0]);
            float p1 = exp2f(s[nf][1]);
            float p2 = exp2f(s[nf][2]);
            float p3 = exp2f(s[nf][3]);
            rs += (p0 + p1) + (p2 + p3);
            unsigned int u01, u23;
            asm("v_cvt_pk_bf16_f32 %0, %1, %2" : "=v"(u01) : "v"(p0), "v"(p1));
            asm("v_cvt_pk_bf16_f32 %0, %1, %2" : "=v"(u23) : "v"(p2), "v"(p3));
            int k0 = nf * 16 + lq * 4;
            int sw = (lr & 7) << 3;
            *(unsigned int*)&pw[lr * 128 + (k0 ^ sw)]       = u01;
            *(unsigned int*)&pw[lr * 128 + ((k0 + 2) ^ sw)] = u23;
        }
#pragma unroll
        for (int ks = 0; ks < 4; ++ks) {
            short8 pf = *(const short8*)&pw[(lr * 128 + ks * 32 + lq * 8) ^ ((lr & 7) << 3)];
            short8 vf = *(const short8*)(vh + (size_t)lr * NR + kbase + ks * 32 + lq * 8);
            oacc = __builtin_amdgcn_mfma_f32_16x16x32_bf16(pf, vf, oacc, 0, 0, 0);
        }
    }
    rs += __shfl_xor(rs, 16);
    rs += __shfl_xor(rs, 32);
    if (w >= 4) {
        comb[w - 4][l][0] = oacc[0];
        comb[w - 4][l][1] = oacc[1];
        comb[w - 4][l][2] = oacc[2];
        comb[w - 4][l][3] = oacc[3];
        comb[w - 4][l][4] = rs;
    }
    __syncthreads();
    if (w < 4) {
        oacc[0] += comb[w][l][0];
        oacc[1] += comb[w][l][1];
        oacc[2] += comb[w][l][2];
        oacc[3] += comb[w][l][3];
        rs += comb[w][l][4];
        float r0 = __shfl(rs, lq * 4 + 0);
        float r1 = __shfl(rs, lq * 4 + 1);
        float r2 = __shfl(rs, lq * 4 + 2);
        float r3 = __shfl(rs, lq * 4 + 3);
        size_t base_o = (size_t)(q0 + lq * 4) * C_DIM + h * HDIM + lr;
        ob[base_o]             = f2b(oacc[0] / r0);
        ob[base_o + C_DIM]     = f2b(oacc[1] / r1);
        ob[base_o + 2 * C_DIM] = f2b(oacc[2] / r2);
        ob[base_o + 3 * C_DIM] = f2b(oacc[3] / r3);
    }
}

// ---------------- final gate: out(C,N) = x * sigmoid(loc + glo) ----------------
__global__ __launch_bounds__(256) void gate_k(const float* __restrict__ x,
                                              const float* __restrict__ lf, const float* __restrict__ gf,
                                              float* __restrict__ out) {
    __shared__ float tile[32][33];
    int n0 = blockIdx.x * 32, c0 = blockIdx.y * 32;
    int tx = threadIdx.x, ty = threadIdx.y;
#pragma unroll
    for (int k = 0; k < 4; ++k) {
        int n = n0 + ty + k * 8, c = c0 + tx;
        tile[ty + k * 8][tx] = lf[(size_t)n * C_DIM + c] + gf[(size_t)n * C_DIM + c];
    }
    __syncthreads();
#pragma unroll
    for (int k = 0; k < 4; ++k) {
        int c = c0 + ty + k * 8, n = n0 + tx;
        float z = tile[tx][ty + k * 8];
        float sg = 1.0f / (1.0f + __expf(-z));
        out[(size_t)c * N_TOK + n] = x[(size_t)c * N_TOK + n] * sg;
    }
}

extern "C" void kernel_launch(void* const* d_in, const int* in_sizes, int n_in,
                              void* d_out, int out_size, void* d_ws, size_t ws_size,
                              hipStream_t stream) {
    const float* x        = (const float*)d_in[0];
    const float* l_n1_g   = (const float*)d_in[1];
    const float* l_n1_b   = (const float*)d_in[2];
    const float* l_qkv_w  = (const float*)d_in[3];
    const float* l_proj_w = (const float*)d_in[4];
    const float* l_proj_b = (const float*)d_in[5];
    const float* l_n2_g   = (const float*)d_in[6];
    const float* l_n2_b   = (const float*)d_in[7];
    const float* l_fc1_w  = (const float*)d_in[8];
    const float* l_fc1_b  = (const float*)d_in[9];
    const float* l_fc2_w  = (const float*)d_in[10];
    const float* l_fc2_b  = (const float*)d_in[11];
    const float* g_n1_g   = (const float*)d_in[12];
    const float* g_n1_b   = (const float*)d_in[13];
    const float* g_qkv_w  = (const float*)d_in[14];
    const float* g_proj_w = (const float*)d_in[15];
    const float* g_proj_b = (const float*)d_in[16];
    const float* g_n2_g   = (const float*)d_in[17];
    const float* g_n2_b   = (const float*)d_in[18];
    const float* g_fc1_w  = (const float*)d_in[19];
    const float* g_fc1_b  = (const float*)d_in[20];
    const float* g_fc2_w  = (const float*)d_in[21];
    const float* g_fc2_b  = (const float*)d_in[22];
    const float* g_ke_w   = (const float*)d_in[23];
    const float* g_ve_w   = (const float*)d_in[24];
    const float* g_nk_g   = (const float*)d_in[25];
    const float* g_nk_b   = (const float*)d_in[26];
    const float* g_nv_g   = (const float*)d_in[27];
    const float* g_nv_b   = (const float*)d_in[28];
    float* out = (float*)d_out;

    char* base = (char*)d_ws;
    float* xt     = (float*)(base);                        // 0-4 MB
    float* t1_l   = (float*)(base + (4ull  << 20));        // 4-8 MB
    float* t1_g   = (float*)(base + (8ull  << 20));        // 8-12 MB
    short* yA16   = (short*)(base + (12ull << 20));        // 12-14 (later t2_l)
    short* yG16   = (short*)(base + (14ull << 20));        // 14-16 (later t2_g)
    short* t2_l   = yA16;
    short* t2_g   = yG16;
    float* locfin = (float*)(base + (12ull << 20));        // 12-16 (after fc1 reads t2)
    short* obuf_l = (short*)(base + (16ull << 20));        // 16-18
    short* obuf_g = (short*)(base + (18ull << 20));        // 18-20
    float* glofin = (float*)(base + (16ull << 20));        // 16-20 (after proj reads obuf)
    short* qkv_l  = (short*)(base + (20ull << 20));        // 20-26
    short* qkv_g  = (short*)(base + (26ull << 20));        // 26-32
    short* h1_l   = (short*)(base + (32ull << 20));        // 32-40 (after ln_head)
    float* kpart  = (float*)(base + (32ull << 20));        // 32-36 (pre-fc1)
    float* vpart  = (float*)(base + (36ull << 20));        // 36-40 (pre-fc1)
    short* h1_g   = (short*)(base + (40ull << 20));        // 40-48
    short* kb16   = (short*)(base + (48ull << 20));        // [8][1024][16]
    short* vt16   = (short*)(base + (48ull << 20) + (512ull << 10)); // [8][16][1024]
    short* wts    = (short*)(base + (49ull << 20));        // ~1.3 MB

    const int L_QKV = 0,      L_PROJ = 49152, L_FC1 = 65536,  L_FC2 = 131072;
    const int G_QKV = 196608, G_PROJ = 245760, G_FC1 = 262144, G_FC2 = 327680;
    const int G_KE  = 393216, G_VE   = 524288;

    CvtArgs ca;
    ca.d[0] = {l_qkv_w,  wts + L_QKV,  49152, 0};
    ca.d[1] = {l_proj_w, wts + L_PROJ, 16384, 0};
    ca.d[2] = {l_fc1_w,  wts + L_FC1,  65536, 0};
    ca.d[3] = {l_fc2_w,  wts + L_FC2,  65536, 0};
    ca.d[4] = {g_qkv_w,  wts + G_QKV,  49152, 0};
    ca.d[5] = {g_proj_w, wts + G_PROJ, 16384, 0};
    ca.d[6] = {g_fc1_w,  wts + G_FC1,  65536, 0};
    ca.d[7] = {g_fc2_w,  wts + G_FC2,  65536, 0};
    ca.d[8] = {g_ke_w,   wts + G_KE,  131072, 1};   // permuted: [co][off*128+ci]
    ca.d[9] = {g_ve_w,   wts + G_VE,  131072, 1};

    // 1: transpose + LN1 + weight cvt (fused)
    prep_k<<<296, 256, 0, stream>>>(x, l_n1_g, l_n1_b, g_n1_g, g_n1_b, xt, yA16, yG16, ca);

    // 2: both qkv GEMMs
    MArgs a_qkv = {{yA16, yG16}, {wts + L_QKV, wts + G_QKV}, {nullptr, nullptr}, {nullptr, nullptr}, {qkv_l, qkv_g}};
    mgemm_k<0><<<dim3(64, 3, 2), 256, 0, stream>>>(a_qkv, N_TOK, 384, 128);

    // 3: conv reductions (inline gather, split-K x8, async-staged) + local attention
    CLArgs cla = {qkv_g, wts + G_KE, wts + G_VE, kpart, vpart, qkv_l, obuf_l};
    convlat_k<<<384, 256, 0, stream>>>(cla);

    // 4: head-LN for K (scaled for exp2) and V^T (coalesced via LDS transpose)
    ln_head_sum_k<<<64, 256, 0, stream>>>(kpart, vpart, g_nk_g, g_nk_b, g_nv_g, g_nv_b, kb16, vt16);

    // 5: global attention (MFMA flash v8)
    gattn_k<<<dim3(128, 8), 512, 0, stream>>>(qkv_g, kb16, vt16, obuf_g);

    // 6: both proj GEMMs (+bias+residual)
    MArgs a_pj = {{obuf_l, obuf_g}, {wts + L_PROJ, wts + G_PROJ}, {l_proj_b, g_proj_b}, {xt, xt}, {t1_l, t1_g}};
    mgemm_k<1><<<dim3(64, 1, 2), 256, 0, stream>>>(a_pj, N_TOK, 128, 128);

    // 7: both second LNs
    ln2_pair_k<<<4096, 256, 0, stream>>>(t1_l, l_n2_g, l_n2_b, t2_l, t1_g, g_n2_g, g_n2_b, t2_g);

    // 8: both fc1 GEMMs (+bias+gelu)
    MArgs a_f1 = {{t2_l, t2_g}, {wts + L_FC1, wts + G_FC1}, {l_fc1_b, g_fc1_b}, {nullptr, nullptr}, {h1_l, h1_g}};
    mgemm_k<2><<<dim3(64, 4, 2), 256, 0, stream>>>(a_f1, N_TOK, 512, 128);

    // 9: both fc2 GEMMs (+bias+residual)
    MArgs a_f2 = {{h1_l, h1_g}, {wts + L_FC2, wts + G_FC2}, {l_fc2_b, g_fc2_b}, {t1_l, t1_g}, {locfin, glofin}};
    mgemm_k<1><<<dim3(64, 1, 2), 256, 0, stream>>>(a_f2, N_TOK, 128, 512);

    // 10: gate
    gate_k<<<dim3(256, 4), dim3(32, 8), 0, stream>>>(x, locfin, glofin, out);
}

// Round 14
// 126.071 us; speedup vs baseline: 1.3868x; 1.0928x over previous
//
#include <hip/hip_runtime.h>
#include <math.h>

#define N_TOK 8192
#define C_DIM 128
#define NHD   8
#define HDIM  16
#define NR    1024
#define EPSV  1e-5f
#define QK_SCALE 0.25f
#define QK_L2E  0.36067376f   /* 0.25 * log2(e) */

typedef __attribute__((ext_vector_type(8))) short short8;
typedef __attribute__((ext_vector_type(4))) float f32x4;

__device__ __forceinline__ float gelu_f(float v) {
    float u = 0.7978845608f * (v + 0.044715f * v * v * v);
    float e = exp2f(2.885390082f * u);
    return v * (e / (e + 1.0f));
}
__device__ __forceinline__ float uaf(unsigned int u) {
    union { unsigned int u; float f; } x; x.u = u; return x.f;
}
__device__ __forceinline__ short f2b(float v) {
    union { float f; unsigned int u; } x; x.f = v;
    unsigned int r = x.u + 0x7fffu + ((x.u >> 16) & 1u);
    return (short)(r >> 16);
}
__device__ __forceinline__ unsigned int pk2(float a, float b) {
    return (unsigned int)(unsigned short)f2b(a) | ((unsigned int)(unsigned short)f2b(b) << 16);
}
__device__ __forceinline__ void ld16bf(const short* p, float* d) {
    uint4 a = *(const uint4*)p;
    uint4 b = *(const uint4*)(p + 8);
    d[0]  = uaf(a.x << 16); d[1]  = uaf(a.x & 0xffff0000u);
    d[2]  = uaf(a.y << 16); d[3]  = uaf(a.y & 0xffff0000u);
    d[4]  = uaf(a.z << 16); d[5]  = uaf(a.z & 0xffff0000u);
    d[6]  = uaf(a.w << 16); d[7]  = uaf(a.w & 0xffff0000u);
    d[8]  = uaf(b.x << 16); d[9]  = uaf(b.x & 0xffff0000u);
    d[10] = uaf(b.y << 16); d[11] = uaf(b.y & 0xffff0000u);
    d[12] = uaf(b.z << 16); d[13] = uaf(b.z & 0xffff0000u);
    d[14] = uaf(b.w << 16); d[15] = uaf(b.w & 0xffff0000u);
}

// async global->LDS, 16B per lane; LDS dest = wave-uniform base + lane*16
__device__ __forceinline__ void gload16(const void* g, void* l) {
    __builtin_amdgcn_global_load_lds(
        (const __attribute__((address_space(1))) unsigned int*)g,
        (__attribute__((address_space(3))) unsigned int*)l, 16, 0, 0);
}

struct CvtDesc { const float* src; short* dst; int n; int pad; };
struct CvtArgs { CvtDesc d[10]; };

// ------- fused: transpose+LN1 (blocks 0..255) + weight cvt (blocks 256..295) --------
__global__ __launch_bounds__(256) void prep_k(const float* __restrict__ x,
                                              const float* __restrict__ g1, const float* __restrict__ b1,
                                              const float* __restrict__ g2, const float* __restrict__ b2,
                                              float* __restrict__ xt,
                                              short* __restrict__ o1, short* __restrict__ o2,
                                              CvtArgs ca) {
    __shared__ float tile[32][132];
    int t = threadIdx.x;
    if (blockIdx.x >= 256) {
        int bid = blockIdx.x - 256;   // 0..39
#pragma unroll 1
        for (int d = 0; d < 10; ++d) {
            CvtDesc dd = ca.d[d];
            if (dd.pad) {
                for (int i = bid * 256 + t; i < dd.n; i += 40 * 256) {
                    int co = i >> 10, qq = i & 1023;
                    dd.dst[co * 1024 + ((qq & 7) << 7) + (qq >> 3)] = f2b(dd.src[i]);
                }
            } else {
                for (int i = bid * 256 + t; i < dd.n; i += 40 * 256)
                    dd.dst[i] = f2b(dd.src[i]);
            }
        }
        return;
    }
    int n0 = blockIdx.x * 32;
#pragma unroll
    for (int k = 0; k < 16; ++k) {
        int f = t + k * 256;
        int n = f & 31, c = f >> 5;
        tile[n][c] = x[(size_t)c * N_TOK + n0 + n];
    }
    __syncthreads();
    int tk = t >> 3, cb = (t & 7) * 16;
    float v[16];
    float s = 0.f, sq = 0.f;
#pragma unroll
    for (int i = 0; i < 16; ++i) {
        v[i] = tile[tk][cb + i];
        s += v[i]; sq += v[i] * v[i];
    }
    s += __shfl_xor(s, 1);  s += __shfl_xor(s, 2);  s += __shfl_xor(s, 4);
    sq += __shfl_xor(sq, 1); sq += __shfl_xor(sq, 2); sq += __shfl_xor(sq, 4);
    float m = s * (1.0f / 128.0f);
    float var = sq * (1.0f / 128.0f) - m * m;
    float rs = rsqrtf(var + EPSV);
    int tok = n0 + tk;
    float* xp = xt + (size_t)tok * C_DIM + cb;
    *(float4*)(xp)      = make_float4(v[0], v[1], v[2], v[3]);
    *(float4*)(xp + 4)  = make_float4(v[4], v[5], v[6], v[7]);
    *(float4*)(xp + 8)  = make_float4(v[8], v[9], v[10], v[11]);
    *(float4*)(xp + 12) = make_float4(v[12], v[13], v[14], v[15]);
    float hA[16], hB[16];
#pragma unroll
    for (int i = 0; i < 16; ++i) {
        float hn = (v[i] - m) * rs;
        hA[i] = hn * g1[cb + i] + b1[cb + i];
        hB[i] = hn * g2[cb + i] + b2[cb + i];
    }
    uint4 ua0 = {pk2(hA[0], hA[1]), pk2(hA[2], hA[3]), pk2(hA[4], hA[5]), pk2(hA[6], hA[7])};
    uint4 ua1 = {pk2(hA[8], hA[9]), pk2(hA[10], hA[11]), pk2(hA[12], hA[13]), pk2(hA[14], hA[15])};
    uint4 ub0 = {pk2(hB[0], hB[1]), pk2(hB[2], hB[3]), pk2(hB[4], hB[5]), pk2(hB[6], hB[7])};
    uint4 ub1 = {pk2(hB[8], hB[9]), pk2(hB[10], hB[11]), pk2(hB[12], hB[13]), pk2(hB[14], hB[15])};
    *(uint4*)(o1 + (size_t)tok * C_DIM + cb)     = ua0;
    *(uint4*)(o1 + (size_t)tok * C_DIM + cb + 8) = ua1;
    *(uint4*)(o2 + (size_t)tok * C_DIM + cb)     = ub0;
    *(uint4*)(o2 + (size_t)tok * C_DIM + cb + 8) = ub1;
}

// ---------------- second LN, paired across branches ----------------
__global__ __launch_bounds__(256) void ln2_pair_k(const float* __restrict__ in0,
                                                  const float* __restrict__ g0, const float* __restrict__ b0,
                                                  short* __restrict__ o0,
                                                  const float* __restrict__ in1,
                                                  const float* __restrict__ g1, const float* __restrict__ b1,
                                                  short* __restrict__ o1) {
    int blk = blockIdx.x;
    bool sel = blk >= 2048;
    blk &= 2047;
    const float* in = sel ? in1 : in0;
    const float* g  = sel ? g1 : g0;
    const float* b  = sel ? b1 : b0;
    short* o        = sel ? o1 : o0;
    int lane = threadIdx.x & 63;
    int n = blk * 4 + (threadIdx.x >> 6);
    float v0 = in[(size_t)n * C_DIM + lane];
    float v1 = in[(size_t)n * C_DIM + 64 + lane];
    float s = v0 + v1, sq = v0 * v0 + v1 * v1;
#pragma unroll
    for (int off = 32; off >= 1; off >>= 1) {
        s += __shfl_xor(s, off);
        sq += __shfl_xor(sq, off);
    }
    float m = s * (1.0f / 128.0f);
    float var = sq * (1.0f / 128.0f) - m * m;
    float rs = rsqrtf(var + EPSV);
    o[(size_t)n * C_DIM + lane]      = f2b((v0 - m) * rs * g[lane] + b[lane]);
    o[(size_t)n * C_DIM + 64 + lane] = f2b((v1 - m) * rs * g[lane + 64] + b[lane + 64]);
}

// ---------------- bf16 MFMA GEMM, BM=64 x BN=128 tile, async 2-phase ----------------
// 4 waves, each 64x32 (acc[4][2]); grid.x = M/64.
// EPI: 0 bf16 out; 1 f32 = acc+bias+res; 2 bf16 = gelu(acc+bias)
struct MArgs {
    const short* A[2]; const short* W[2];
    const float* bias[2]; const float* res[2];
    void* out[2];
};
template <int EPI>
__global__ __launch_bounds__(256) void mgemm_k(MArgs ga, int M, int N, int K) {
    int zi = blockIdx.z;
    const short* A = ga.A[zi];
    const short* W = ga.W[zi];
    __shared__ short As[2][64 * 64];     // 8 KB each
    __shared__ short Bs[2][128 * 64];    // 16 KB each
    int t = threadIdx.x;
    int w = t >> 6, l = t & 63;
    int m0 = blockIdx.x * 64, n0 = blockIdx.y * 128;
    int wn = w * 32;

    f32x4 acc[4][2];
#pragma unroll
    for (int a = 0; a < 4; ++a)
#pragma unroll
        for (int b = 0; b < 2; ++b) acc[a][b] = f32x4{0.f, 0.f, 0.f, 0.f};

    // pre-swizzled-source staging: LDS linear per wave, global addr carries the XOR
    auto STAGE = [&](int buf, int k0) {
#pragma unroll
        for (int c = 0; c < 2; ++c) {
            int g0 = c * 256 + w * 64;
            int g  = g0 + l;
            int row = g >> 3, ss = g & 7;
            int slot = ss ^ (row & 7);
            gload16(A + (size_t)(m0 + row) * K + k0 + slot * 8, &As[buf][g0 * 8]);
        }
#pragma unroll
        for (int c = 0; c < 4; ++c) {
            int g0 = c * 256 + w * 64;
            int g  = g0 + l;
            int row = g >> 3, ss = g & 7;
            int slot = ss ^ (row & 7);
            gload16(W + (size_t)(n0 + row) * K + k0 + slot * 8, &Bs[buf][g0 * 8]);
        }
    };

    int NT = K >> 6;
    STAGE(0, 0);
    int cur = 0;
    for (int it = 0; it < NT; ++it) {
        if (it + 1 < NT) {
            STAGE(cur ^ 1, (it + 1) << 6);
            asm volatile("s_waitcnt vmcnt(6)" ::: "memory");   // current tile landed
        } else {
            asm volatile("s_waitcnt vmcnt(0)" ::: "memory");
        }
        __builtin_amdgcn_s_barrier();
#pragma unroll
        for (int kk = 0; kk < 2; ++kk) {
            short8 af[4], bf[2];
            int sl = kk * 4 + (l >> 4);
#pragma unroll
            for (int mf = 0; mf < 4; ++mf) {
                int row = mf * 16 + (l & 15);
                af[mf] = *(const short8*)(&As[cur][row * 64 + (sl ^ (row & 7)) * 8]);
            }
#pragma unroll
            for (int nf = 0; nf < 2; ++nf) {
                int row = wn + nf * 16 + (l & 15);
                bf[nf] = *(const short8*)(&Bs[cur][row * 64 + (sl ^ (row & 7)) * 8]);
            }
#pragma unroll
            for (int mf = 0; mf < 4; ++mf)
#pragma unroll
                for (int nf = 0; nf < 2; ++nf)
                    acc[mf][nf] = __builtin_amdgcn_mfma_f32_16x16x32_bf16(
                        af[mf], bf[nf], acc[mf][nf], 0, 0, 0);
        }
        asm volatile("s_waitcnt lgkmcnt(0)" ::: "memory");
        __builtin_amdgcn_sched_barrier(0);
        __builtin_amdgcn_s_barrier();
        cur ^= 1;
    }

    // C/D layout: col = lane&15, row = (lane>>4)*4 + reg
#pragma unroll
    for (int mf = 0; mf < 4; ++mf) {
#pragma unroll
        for (int nf = 0; nf < 2; ++nf) {
            int col = n0 + wn + nf * 16 + (l & 15);
#pragma unroll
            for (int j = 0; j < 4; ++j) {
                int row = m0 + mf * 16 + (l >> 4) * 4 + j;
                float v = acc[mf][nf][j];
                if (EPI == 0) {
                    ((short*)ga.out[zi])[(size_t)row * N + col] = f2b(v);
                } else if (EPI == 1) {
                    v += ga.bias[zi][col] + ga.res[zi][(size_t)row * N + col];
                    ((float*)ga.out[zi])[(size_t)row * N + col] = v;
                } else if (EPI == 2) {
                    v = gelu_f(v + ga.bias[zi][col]);
                    ((short*)ga.out[zi])[(size_t)row * N + col] = f2b(v);
                }
            }
        }
    }
}

// ------- fused: conv reductions w/ inline gather (blocks 0..255, BM=64) + local attn -
struct CLArgs {
    const short* qkv_g; const short* wk; const short* wv;
    float* kpart; float* vpart;
    const short* qkv_l; short* ob;
};
__global__ __launch_bounds__(256) void convlat_k(CLArgs ga) {
    __shared__ char smem[65536];
    int t = threadIdx.x;
    if (blockIdx.x < 256) {
        int bid = blockIdx.x;
        int m0 = (bid & 15) * 64;       // 16 m-blocks of 64 rows
        int slice = (bid >> 4) & 7;     // K-slice (off value)
        int zi = bid >> 7;              // 0 = K-conv, 1 = V-conv
        const short* Abase = ga.qkv_g + (zi ? 256 : 128);
        const short* W = zi ? ga.wv : ga.wk;
        float* outp = zi ? ga.vpart : ga.kpart;
        short (*As)[64 * 64]  = (short(*)[64 * 64])smem;             // 2 x 8 KB
        short (*Bs)[128 * 64] = (short(*)[128 * 64])(smem + 16384);  // 2 x 16 KB
        int w = t >> 6, l = t & 63;
        int wn = w * 32;
        int kbeg = slice * 128;
        int od = slice >> 2, oh = (slice >> 1) & 1, ow = slice & 1;

        f32x4 acc[4][2];
#pragma unroll
        for (int a = 0; a < 4; ++a)
#pragma unroll
            for (int b = 0; b < 2; ++b) acc[a][b] = f32x4{0.f, 0.f, 0.f, 0.f};

        auto STAGE = [&](int buf, int k0) {
#pragma unroll
            for (int c = 0; c < 2; ++c) {
                int g0 = c * 256 + w * 64;
                int g  = g0 + l;
                int row = g >> 3, ss = g & 7;
                int slot = ss ^ (row & 7);
                int nr = m0 + row;
                int n = (2 * (nr >> 8) + od) * 1024 + (2 * ((nr >> 4) & 15) + oh) * 32
                        + 2 * (nr & 15) + ow;
                gload16(Abase + (size_t)n * 384 + (k0 & 127) + slot * 8, &As[buf][g0 * 8]);
            }
#pragma unroll
            for (int c = 0; c < 4; ++c) {
                int g0 = c * 256 + w * 64;
                int g  = g0 + l;
                int row = g >> 3, ss = g & 7;
                int slot = ss ^ (row & 7);
                gload16(W + (size_t)row * 1024 + k0 + slot * 8, &Bs[buf][g0 * 8]);
            }
        };

        STAGE(0, kbeg);
        int cur = 0;
        for (int it = 0; it < 2; ++it) {
            if (it == 0) {
                STAGE(1, kbeg + 64);
                asm volatile("s_waitcnt vmcnt(6)" ::: "memory");
            } else {
                asm volatile("s_waitcnt vmcnt(0)" ::: "memory");
            }
            __builtin_amdgcn_s_barrier();
#pragma unroll
            for (int kk = 0; kk < 2; ++kk) {
                short8 af[4], bf[2];
                int sl = kk * 4 + (l >> 4);
#pragma unroll
                for (int mf = 0; mf < 4; ++mf) {
                    int row = mf * 16 + (l & 15);
                    af[mf] = *(const short8*)(&As[cur][row * 64 + (sl ^ (row & 7)) * 8]);
                }
#pragma unroll
                for (int nf = 0; nf < 2; ++nf) {
                    int row = wn + nf * 16 + (l & 15);
                    bf[nf] = *(const short8*)(&Bs[cur][row * 64 + (sl ^ (row & 7)) * 8]);
                }
#pragma unroll
                for (int mf = 0; mf < 4; ++mf)
#pragma unroll
                    for (int nf = 0; nf < 2; ++nf)
                        acc[mf][nf] = __builtin_amdgcn_mfma_f32_16x16x32_bf16(
                            af[mf], bf[nf], acc[mf][nf], 0, 0, 0);
            }
            asm volatile("s_waitcnt lgkmcnt(0)" ::: "memory");
            __builtin_amdgcn_sched_barrier(0);
            __builtin_amdgcn_s_barrier();
            cur ^= 1;
        }
#pragma unroll
        for (int mf = 0; mf < 4; ++mf)
#pragma unroll
            for (int nf = 0; nf < 2; ++nf) {
                int col = wn + nf * 16 + (l & 15);
#pragma unroll
                for (int j = 0; j < 4; ++j) {
                    int row = m0 + mf * 16 + (l >> 4) * 4 + j;
                    outp[(size_t)slice * (NR * C_DIM) + (size_t)row * C_DIM + col] =
                        acc[mf][nf][j];
                }
            }
        return;
    }
    float (*ks)[32][HDIM] = (float(*)[32][HDIM])smem;
    float (*vs)[32][HDIM] = (float(*)[32][HDIM])(smem + 16384);
    int m = t & 31, h = t >> 5, r = blockIdx.x - 256;
    int zd = r >> 6, zh = (r >> 3) & 7, zw = r & 7;
    int pd = m >> 4, ph = (m >> 2) & 3, pw = m & 3;
    int n = (zd * 2 + pd) * 1024 + (zh * 4 + ph) * 32 + (zw * 4 + pw);
    const short* base = ga.qkv_l + (size_t)n * 384 + h * HDIM;
    float q[16], kt[16], vt[16];
    ld16bf(base, q);
    ld16bf(base + 128, kt);
    ld16bf(base + 256, vt);
#pragma unroll
    for (int d = 0; d < 16; ++d) { ks[h][m][d] = kt[d]; vs[h][m][d] = vt[d]; }
    __syncthreads();
    float s[32];
#pragma unroll
    for (int j = 0; j < 32; ++j) {
        float d = 0.f;
#pragma unroll
        for (int dd = 0; dd < 16; ++dd) d += q[dd] * ks[h][j][dd];
        s[j] = __expf(d * QK_SCALE);
    }
    float sum = 0.f;
#pragma unroll
    for (int j = 0; j < 32; ++j) sum += s[j];
    float inv = 1.0f / sum;
    float oo[16] = {};
#pragma unroll
    for (int j = 0; j < 32; ++j) {
        float p = s[j] * inv;
#pragma unroll
        for (int dd = 0; dd < 16; ++dd) oo[dd] += p * vs[h][j][dd];
    }
#pragma unroll
    for (int dd = 0; dd < 16; ++dd) {
        int n2 = h * 4 + (dd >> 2);
        int c2 = (dd & 3) * 32 + m;
        int pd2 = n2 >> 4, ph2 = (n2 >> 2) & 3, pw2 = n2 & 3;
        int nn = (zd * 2 + pd2) * 1024 + (zh * 4 + ph2) * 32 + (zw * 4 + pw2);
        ga.ob[(size_t)nn * C_DIM + c2] = f2b(oo[dd]);
    }
}

// ------- sum 8 split-K partials + per-head LN; K -> bf16 *0.25*log2e, V -> bf16^T ---
__global__ __launch_bounds__(256) void ln_head_sum_k(const float* __restrict__ kpart,
                                                     const float* __restrict__ vpart,
                                                     const float* __restrict__ gk, const float* __restrict__ bk,
                                                     const float* __restrict__ gv, const float* __restrict__ bv,
                                                     short* __restrict__ kout, short* __restrict__ vout) {
    __shared__ float vlds[8][16][33];
    int t = threadIdx.x;
    bool sel = blockIdx.x >= 32;
    int b = sel ? (blockIdx.x - 32) : blockIdx.x;
    int id2 = b * 256 + t;
    const float* part = sel ? vpart : kpart;
    const float* g    = sel ? gv : gk;
    const float* bb   = sel ? bv : bk;
    int nr = id2 >> 3, h = id2 & 7;
    size_t base = (size_t)nr * C_DIM + h * HDIM;
    float v[16] = {};
#pragma unroll
    for (int p = 0; p < 8; ++p) {
        const float* pp = part + (size_t)p * (NR * C_DIM) + base;
#pragma unroll
        for (int d4 = 0; d4 < 4; ++d4) {
            float4 tv = *(const float4*)(pp + d4 * 4);
            v[d4 * 4 + 0] += tv.x; v[d4 * 4 + 1] += tv.y;
            v[d4 * 4 + 2] += tv.z; v[d4 * 4 + 3] += tv.w;
        }
    }
    float s = 0.f;
#pragma unroll
    for (int i = 0; i < 16; ++i) s += v[i];
    float m = s * (1.0f / 16.0f);
    float sq = 0.f;
#pragma unroll
    for (int i = 0; i < 16; ++i) { float d = v[i] - m; sq += d * d; }
    float rs = rsqrtf(sq * (1.0f / 16.0f) + EPSV);
    if (!sel) {
        short* op = kout + (size_t)h * (NR * HDIM) + (size_t)nr * HDIM;
#pragma unroll
        for (int i = 0; i < 16; ++i)
            op[i] = f2b(((v[i] - m) * rs * g[i] + bb[i]) * QK_L2E);
        return;
    }
    int nr_l = t >> 3;               // 0..31  (h = t&7)
#pragma unroll
    for (int i = 0; i < 16; ++i)
        vlds[h][i][nr_l] = (v[i] - m) * rs * g[i] + bb[i];
    __syncthreads();
    int row = t >> 1, half = t & 1;  // 128 rows = (h2,i2); 2 threads/row
    int h2 = row >> 4, i2 = row & 15;
    const float* src = &vlds[h2][i2][half * 16];
    uint4 u0 = {pk2(src[0], src[1]), pk2(src[2], src[3]), pk2(src[4], src[5]), pk2(src[6], src[7])};
    uint4 u1 = {pk2(src[8], src[9]), pk2(src[10], src[11]), pk2(src[12], src[13]), pk2(src[14], src[15])};
    short* dst = vout + (size_t)h2 * (HDIM * NR) + (size_t)i2 * NR + b * 32 + half * 16;
    *(uint4*)(dst)     = u0;
    *(uint4*)(dst + 8) = u1;
}

// ---------------- global attention v8: 8 waves, split-K wave pairs ----------------
__global__ __launch_bounds__(512) void gattn_k(const short* __restrict__ qkv,
                                               const short* __restrict__ kb,   // [8][1024][16] *0.25*log2e
                                               const short* __restrict__ vt,   // [8][16][1024]
                                               short* __restrict__ ob) {
    __shared__ short plds[8][2048];
    __shared__ float comb[4][64][5];
    int t = threadIdx.x;
    int w = t >> 6, l = t & 63;
    int h = blockIdx.y;
    int lr = l & 15, lq = l >> 4;
    int qw = w & 3, kw = w >> 2;
    int q0 = blockIdx.x * 64 + qw * 16;

    short8 qf = short8{0, 0, 0, 0, 0, 0, 0, 0};
    if (lq < 2)
        qf = *(const short8*)(qkv + (size_t)(q0 + lr) * 384 + h * HDIM + lq * 8);

    const short* kh = kb + (size_t)h * (NR * HDIM);
    const short* vh = vt + (size_t)h * (HDIM * NR);
    short* pw = &plds[w][0];

    const f32x4 zz = {0.f, 0.f, 0.f, 0.f};
    f32x4 oacc = {0.f, 0.f, 0.f, 0.f};
    float rs = 0.f;

    for (int c = 0; c < 4; ++c) {
        int kbase = kw * 512 + c * 128;
        f32x4 s[8];
#pragma unroll
        for (int nf = 0; nf < 8; ++nf) {
            short8 kf = short8{0, 0, 0, 0, 0, 0, 0, 0};
            if (lq < 2)
                kf = *(const short8*)(kh + (size_t)(kbase + nf * 16 + lr) * HDIM + lq * 8);
            s[nf] = __builtin_amdgcn_mfma_f32_16x16x32_bf16(kf, qf, zz, 0, 0, 0);
        }
#pragma unroll
        for (int nf = 0; nf < 8; ++nf) {
            float p0 = exp2f(s[nf][0]);
            float p1 = exp2f(s[nf][1]);
            float p2 = exp2f(s[nf][2]);
            float p3 = exp2f(s[nf][3]);
            rs += (p0 + p1) + (p2 + p3);
            unsigned int u01, u23;
            asm("v_cvt_pk_bf16_f32 %0, %1, %2" : "=v"(u01) : "v"(p0), "v"(p1));
            asm("v_cvt_pk_bf16_f32 %0, %1, %2" : "=v"(u23) : "v"(p2), "v"(p3));
            int k0 = nf * 16 + lq * 4;
            int sw = (lr & 7) << 3;
            *(unsigned int*)&pw[lr * 128 + (k0 ^ sw)]       = u01;
            *(unsigned int*)&pw[lr * 128 + ((k0 + 2) ^ sw)] = u23;
        }
#pragma unroll
        for (int ks = 0; ks < 4; ++ks) {
            short8 pf = *(const short8*)&pw[(lr * 128 + ks * 32 + lq * 8) ^ ((lr & 7) << 3)];
            short8 vf = *(const short8*)(vh + (size_t)lr * NR + kbase + ks * 32 + lq * 8);
            oacc = __builtin_amdgcn_mfma_f32_16x16x32_bf16(pf, vf, oacc, 0, 0, 0);
        }
    }
    rs += __shfl_xor(rs, 16);
    rs += __shfl_xor(rs, 32);
    if (w >= 4) {
        comb[w - 4][l][0] = oacc[0];
        comb[w - 4][l][1] = oacc[1];
        comb[w - 4][l][2] = oacc[2];
        comb[w - 4][l][3] = oacc[3];
        comb[w - 4][l][4] = rs;
    }
    __syncthreads();
    if (w < 4) {
        oacc[0] += comb[w][l][0];
        oacc[1] += comb[w][l][1];
        oacc[2] += comb[w][l][2];
        oacc[3] += comb[w][l][3];
        rs += comb[w][l][4];
        float r0 = __shfl(rs, lq * 4 + 0);
        float r1 = __shfl(rs, lq * 4 + 1);
        float r2 = __shfl(rs, lq * 4 + 2);
        float r3 = __shfl(rs, lq * 4 + 3);
        size_t base_o = (size_t)(q0 + lq * 4) * C_DIM + h * HDIM + lr;
        ob[base_o]             = f2b(oacc[0] / r0);
        ob[base_o + C_DIM]     = f2b(oacc[1] / r1);
        ob[base_o + 2 * C_DIM] = f2b(oacc[2] / r2);
        ob[base_o + 3 * C_DIM] = f2b(oacc[3] / r3);
    }
}

// ---------------- final gate: out(C,N) = x * sigmoid(loc + glo) ----------------
__global__ __launch_bounds__(256) void gate_k(const float* __restrict__ x,
                                              const float* __restrict__ lf, const float* __restrict__ gf,
                                              float* __restrict__ out) {
    __shared__ float tile[32][33];
    int n0 = blockIdx.x * 32, c0 = blockIdx.y * 32;
    int tx = threadIdx.x, ty = threadIdx.y;
#pragma unroll
    for (int k = 0; k < 4; ++k) {
        int n = n0 + ty + k * 8, c = c0 + tx;
        tile[ty + k * 8][tx] = lf[(size_t)n * C_DIM + c] + gf[(size_t)n * C_DIM + c];
    }
    __syncthreads();
#pragma unroll
    for (int k = 0; k < 4; ++k) {
        int c = c0 + ty + k * 8, n = n0 + tx;
        float z = tile[tx][ty + k * 8];
        float sg = 1.0f / (1.0f + __expf(-z));
        out[(size_t)c * N_TOK + n] = x[(size_t)c * N_TOK + n] * sg;
    }
}

extern "C" void kernel_launch(void* const* d_in, const int* in_sizes, int n_in,
                              void* d_out, int out_size, void* d_ws, size_t ws_size,
                              hipStream_t stream) {
    const float* x        = (const float*)d_in[0];
    const float* l_n1_g   = (const float*)d_in[1];
    const float* l_n1_b   = (const float*)d_in[2];
    const float* l_qkv_w  = (const float*)d_in[3];
    const float* l_proj_w = (const float*)d_in[4];
    const float* l_proj_b = (const float*)d_in[5];
    const float* l_n2_g   = (const float*)d_in[6];
    const float* l_n2_b   = (const float*)d_in[7];
    const float* l_fc1_w  = (const float*)d_in[8];
    const float* l_fc1_b  = (const float*)d_in[9];
    const float* l_fc2_w  = (const float*)d_in[10];
    const float* l_fc2_b  = (const float*)d_in[11];
    const float* g_n1_g   = (const float*)d_in[12];
    const float* g_n1_b   = (const float*)d_in[13];
    const float* g_qkv_w  = (const float*)d_in[14];
    const float* g_proj_w = (const float*)d_in[15];
    const float* g_proj_b = (const float*)d_in[16];
    const float* g_n2_g   = (const float*)d_in[17];
    const float* g_n2_b   = (const float*)d_in[18];
    const float* g_fc1_w  = (const float*)d_in[19];
    const float* g_fc1_b  = (const float*)d_in[20];
    const float* g_fc2_w  = (const float*)d_in[21];
    const float* g_fc2_b  = (const float*)d_in[22];
    const float* g_ke_w   = (const float*)d_in[23];
    const float* g_ve_w   = (const float*)d_in[24];
    const float* g_nk_g   = (const float*)d_in[25];
    const float* g_nk_b   = (const float*)d_in[26];
    const float* g_nv_g   = (const float*)d_in[27];
    const float* g_nv_b   = (const float*)d_in[28];
    float* out = (float*)d_out;

    char* base = (char*)d_ws;
    float* xt     = (float*)(base);                        // 0-4 MB
    float* t1_l   = (float*)(base + (4ull  << 20));        // 4-8 MB
    float* t1_g   = (float*)(base + (8ull  << 20));        // 8-12 MB
    short* yA16   = (short*)(base + (12ull << 20));        // 12-14 (later t2_l)
    short* yG16   = (short*)(base + (14ull << 20));        // 14-16 (later t2_g)
    short* t2_l   = yA16;
    short* t2_g   = yG16;
    float* locfin = (float*)(base + (12ull << 20));        // 12-16 (after fc1 reads t2)
    short* obuf_l = (short*)(base + (16ull << 20));        // 16-18
    short* obuf_g = (short*)(base + (18ull << 20));        // 18-20
    float* glofin = (float*)(base + (16ull << 20));        // 16-20 (after proj reads obuf)
    short* qkv_l  = (short*)(base + (20ull << 20));        // 20-26
    short* qkv_g  = (short*)(base + (26ull << 20));        // 26-32
    short* h1_l   = (short*)(base + (32ull << 20));        // 32-40 (after ln_head)
    float* kpart  = (float*)(base + (32ull << 20));        // 32-36 (pre-fc1)
    float* vpart  = (float*)(base + (36ull << 20));        // 36-40 (pre-fc1)
    short* h1_g   = (short*)(base + (40ull << 20));        // 40-48
    short* kb16   = (short*)(base + (48ull << 20));        // [8][1024][16]
    short* vt16   = (short*)(base + (48ull << 20) + (512ull << 10)); // [8][16][1024]
    short* wts    = (short*)(base + (49ull << 20));        // ~1.3 MB

    const int L_QKV = 0,      L_PROJ = 49152, L_FC1 = 65536,  L_FC2 = 131072;
    const int G_QKV = 196608, G_PROJ = 245760, G_FC1 = 262144, G_FC2 = 327680;
    const int G_KE  = 393216, G_VE   = 524288;

    CvtArgs ca;
    ca.d[0] = {l_qkv_w,  wts + L_QKV,  49152, 0};
    ca.d[1] = {l_proj_w, wts + L_PROJ, 16384, 0};
    ca.d[2] = {l_fc1_w,  wts + L_FC1,  65536, 0};
    ca.d[3] = {l_fc2_w,  wts + L_FC2,  65536, 0};
    ca.d[4] = {g_qkv_w,  wts + G_QKV,  49152, 0};
    ca.d[5] = {g_proj_w, wts + G_PROJ, 16384, 0};
    ca.d[6] = {g_fc1_w,  wts + G_FC1,  65536, 0};
    ca.d[7] = {g_fc2_w,  wts + G_FC2,  65536, 0};
    ca.d[8] = {g_ke_w,   wts + G_KE,  131072, 1};   // permuted: [co][off*128+ci]
    ca.d[9] = {g_ve_w,   wts + G_VE,  131072, 1};

    // 1: transpose + LN1 + weight cvt (fused)
    prep_k<<<296, 256, 0, stream>>>(x, l_n1_g, l_n1_b, g_n1_g, g_n1_b, xt, yA16, yG16, ca);

    // 2: both qkv GEMMs (BM=64 -> 768 blocks)
    MArgs a_qkv = {{yA16, yG16}, {wts + L_QKV, wts + G_QKV}, {nullptr, nullptr}, {nullptr, nullptr}, {qkv_l, qkv_g}};
    mgemm_k<0><<<dim3(128, 3, 2), 256, 0, stream>>>(a_qkv, N_TOK, 384, 128);

    // 3: conv reductions (BM=64, inline gather, split-K x8) + local attention (512 blocks)
    CLArgs cla = {qkv_g, wts + G_KE, wts + G_VE, kpart, vpart, qkv_l, obuf_l};
    convlat_k<<<512, 256, 0, stream>>>(cla);

    // 4: head-LN for K (scaled for exp2) and V^T (coalesced via LDS transpose)
    ln_head_sum_k<<<64, 256, 0, stream>>>(kpart, vpart, g_nk_g, g_nk_b, g_nv_g, g_nv_b, kb16, vt16);

    // 5: global attention (MFMA flash v8)
    gattn_k<<<dim3(128, 8), 512, 0, stream>>>(qkv_g, kb16, vt16, obuf_g);

    // 6: both proj GEMMs (+bias+residual) (BM=64 -> 256 blocks)
    MArgs a_pj = {{obuf_l, obuf_g}, {wts + L_PROJ, wts + G_PROJ}, {l_proj_b, g_proj_b}, {xt, xt}, {t1_l, t1_g}};
    mgemm_k<1><<<dim3(128, 1, 2), 256, 0, stream>>>(a_pj, N_TOK, 128, 128);

    // 7: both second LNs
    ln2_pair_k<<<4096, 256, 0, stream>>>(t1_l, l_n2_g, l_n2_b, t2_l, t1_g, g_n2_g, g_n2_b, t2_g);

    // 8: both fc1 GEMMs (+bias+gelu) (BM=64 -> 1024 blocks)
    MArgs a_f1 = {{t2_l, t2_g}, {wts + L_FC1, wts + G_FC1}, {l_fc1_b, g_fc1_b}, {nullptr, nullptr}, {h1_l, h1_g}};
    mgemm_k<2><<<dim3(128, 4, 2), 256, 0, stream>>>(a_f1, N_TOK, 512, 128);

    // 9: both fc2 GEMMs (+bias+residual) (BM=64 -> 256 blocks)
    MArgs a_f2 = {{h1_l, h1_g}, {wts + L_FC2, wts + G_FC2}, {l_fc2_b, g_fc2_b}, {t1_l, t1_g}, {locfin, glofin}};
    mgemm_k<1><<<dim3(128, 1, 2), 256, 0, stream>>>(a_f2, N_TOK, 128, 512);

    // 10: gate
    gate_k<<<dim3(256, 4), dim3(32, 8), 0, stream>>>(x, locfin, glofin, out);
}

// Round 15
// 120.476 us; speedup vs baseline: 1.4512x; 1.0464x over previous
//
#include <hip/hip_runtime.h>
#include <math.h>

#define N_TOK 8192
#define C_DIM 128
#define NHD   8
#define HDIM  16
#define NR    1024
#define EPSV  1e-5f
#define QK_SCALE 0.25f
#define QK_L2E  0.36067376f   /* 0.25 * log2(e) */

typedef __attribute__((ext_vector_type(8))) short short8;
typedef __attribute__((ext_vector_type(4))) float f32x4;

__device__ __forceinline__ float gelu_f(float v) {
    float u = 0.7978845608f * (v + 0.044715f * v * v * v);
    float e = exp2f(2.885390082f * u);
    return v * (e / (e + 1.0f));
}
__device__ __forceinline__ float uaf(unsigned int u) {
    union { unsigned int u; float f; } x; x.u = u; return x.f;
}
__device__ __forceinline__ short f2b(float v) {
    union { float f; unsigned int u; } x; x.f = v;
    unsigned int r = x.u + 0x7fffu + ((x.u >> 16) & 1u);
    return (short)(r >> 16);
}
__device__ __forceinline__ unsigned int pk2(float a, float b) {
    return (unsigned int)(unsigned short)f2b(a) | ((unsigned int)(unsigned short)f2b(b) << 16);
}
__device__ __forceinline__ void ld16bf(const short* p, float* d) {
    uint4 a = *(const uint4*)p;
    uint4 b = *(const uint4*)(p + 8);
    d[0]  = uaf(a.x << 16); d[1]  = uaf(a.x & 0xffff0000u);
    d[2]  = uaf(a.y << 16); d[3]  = uaf(a.y & 0xffff0000u);
    d[4]  = uaf(a.z << 16); d[5]  = uaf(a.z & 0xffff0000u);
    d[6]  = uaf(a.w << 16); d[7]  = uaf(a.w & 0xffff0000u);
    d[8]  = uaf(b.x << 16); d[9]  = uaf(b.x & 0xffff0000u);
    d[10] = uaf(b.y << 16); d[11] = uaf(b.y & 0xffff0000u);
    d[12] = uaf(b.z << 16); d[13] = uaf(b.z & 0xffff0000u);
    d[14] = uaf(b.w << 16); d[15] = uaf(b.w & 0xffff0000u);
}

// async global->LDS, 16B per lane; LDS dest = wave-uniform base + lane*16
__device__ __forceinline__ void gload16(const void* g, void* l) {
    __builtin_amdgcn_global_load_lds(
        (const __attribute__((address_space(1))) unsigned int*)g,
        (__attribute__((address_space(3))) unsigned int*)l, 16, 0, 0);
}

struct CvtDesc { const float* src; short* dst; int n; int pad; };
struct CvtArgs { CvtDesc d[10]; };

// ------- fused: transpose+LN1 (blocks 0..255) + weight cvt (blocks 256..295) --------
__global__ __launch_bounds__(256) void prep_k(const float* __restrict__ x,
                                              const float* __restrict__ g1, const float* __restrict__ b1,
                                              const float* __restrict__ g2, const float* __restrict__ b2,
                                              float* __restrict__ xt,
                                              short* __restrict__ o1, short* __restrict__ o2,
                                              CvtArgs ca) {
    __shared__ float tile[32][132];
    int t = threadIdx.x;
    if (blockIdx.x >= 256) {
        int bid = blockIdx.x - 256;   // 0..39
#pragma unroll 1
        for (int d = 0; d < 10; ++d) {
            CvtDesc dd = ca.d[d];
            if (dd.pad) {
                for (int i = bid * 256 + t; i < dd.n; i += 40 * 256) {
                    int co = i >> 10, qq = i & 1023;
                    dd.dst[co * 1024 + ((qq & 7) << 7) + (qq >> 3)] = f2b(dd.src[i]);
                }
            } else {
                for (int i = bid * 256 + t; i < dd.n; i += 40 * 256)
                    dd.dst[i] = f2b(dd.src[i]);
            }
        }
        return;
    }
    int n0 = blockIdx.x * 32;
#pragma unroll
    for (int k = 0; k < 16; ++k) {
        int f = t + k * 256;
        int n = f & 31, c = f >> 5;
        tile[n][c] = x[(size_t)c * N_TOK + n0 + n];
    }
    __syncthreads();
    int tk = t >> 3, cb = (t & 7) * 16;
    float v[16];
    float s = 0.f, sq = 0.f;
#pragma unroll
    for (int i = 0; i < 16; ++i) {
        v[i] = tile[tk][cb + i];
        s += v[i]; sq += v[i] * v[i];
    }
    s += __shfl_xor(s, 1);  s += __shfl_xor(s, 2);  s += __shfl_xor(s, 4);
    sq += __shfl_xor(sq, 1); sq += __shfl_xor(sq, 2); sq += __shfl_xor(sq, 4);
    float m = s * (1.0f / 128.0f);
    float var = sq * (1.0f / 128.0f) - m * m;
    float rs = rsqrtf(var + EPSV);
    int tok = n0 + tk;
    float* xp = xt + (size_t)tok * C_DIM + cb;
    *(float4*)(xp)      = make_float4(v[0], v[1], v[2], v[3]);
    *(float4*)(xp + 4)  = make_float4(v[4], v[5], v[6], v[7]);
    *(float4*)(xp + 8)  = make_float4(v[8], v[9], v[10], v[11]);
    *(float4*)(xp + 12) = make_float4(v[12], v[13], v[14], v[15]);
    float hA[16], hB[16];
#pragma unroll
    for (int i = 0; i < 16; ++i) {
        float hn = (v[i] - m) * rs;
        hA[i] = hn * g1[cb + i] + b1[cb + i];
        hB[i] = hn * g2[cb + i] + b2[cb + i];
    }
    uint4 ua0 = {pk2(hA[0], hA[1]), pk2(hA[2], hA[3]), pk2(hA[4], hA[5]), pk2(hA[6], hA[7])};
    uint4 ua1 = {pk2(hA[8], hA[9]), pk2(hA[10], hA[11]), pk2(hA[12], hA[13]), pk2(hA[14], hA[15])};
    uint4 ub0 = {pk2(hB[0], hB[1]), pk2(hB[2], hB[3]), pk2(hB[4], hB[5]), pk2(hB[6], hB[7])};
    uint4 ub1 = {pk2(hB[8], hB[9]), pk2(hB[10], hB[11]), pk2(hB[12], hB[13]), pk2(hB[14], hB[15])};
    *(uint4*)(o1 + (size_t)tok * C_DIM + cb)     = ua0;
    *(uint4*)(o1 + (size_t)tok * C_DIM + cb + 8) = ua1;
    *(uint4*)(o2 + (size_t)tok * C_DIM + cb)     = ub0;
    *(uint4*)(o2 + (size_t)tok * C_DIM + cb + 8) = ub1;
}

// ---------------- second LN, paired across branches ----------------
__global__ __launch_bounds__(256) void ln2_pair_k(const float* __restrict__ in0,
                                                  const float* __restrict__ g0, const float* __restrict__ b0,
                                                  short* __restrict__ o0,
                                                  const float* __restrict__ in1,
                                                  const float* __restrict__ g1, const float* __restrict__ b1,
                                                  short* __restrict__ o1) {
    int blk = blockIdx.x;
    bool sel = blk >= 2048;
    blk &= 2047;
    const float* in = sel ? in1 : in0;
    const float* g  = sel ? g1 : g0;
    const float* b  = sel ? b1 : b0;
    short* o        = sel ? o1 : o0;
    int lane = threadIdx.x & 63;
    int n = blk * 4 + (threadIdx.x >> 6);
    float v0 = in[(size_t)n * C_DIM + lane];
    float v1 = in[(size_t)n * C_DIM + 64 + lane];
    float s = v0 + v1, sq = v0 * v0 + v1 * v1;
#pragma unroll
    for (int off = 32; off >= 1; off >>= 1) {
        s += __shfl_xor(s, off);
        sq += __shfl_xor(sq, off);
    }
    float m = s * (1.0f / 128.0f);
    float var = sq * (1.0f / 128.0f) - m * m;
    float rs = rsqrtf(var + EPSV);
    o[(size_t)n * C_DIM + lane]      = f2b((v0 - m) * rs * g[lane] + b[lane]);
    o[(size_t)n * C_DIM + 64 + lane] = f2b((v1 - m) * rs * g[lane + 64] + b[lane + 64]);
}

// ---------------- bf16 MFMA GEMM, BM=64 x BN={128,64} tile, async 2-phase -----------
// 4 waves, each 64 x (BN/4); grid = (M/64, N/BN, 2).
// EPI: 0 bf16 out; 1 f32 = acc+bias+res; 2 bf16 = gelu(acc+bias)
struct MArgs {
    const short* A[2]; const short* W[2];
    const float* bias[2]; const float* res[2];
    void* out[2];
};
template <int EPI, int BN>
__global__ __launch_bounds__(256) void mgemm_k(MArgs ga, int M, int N, int K) {
    constexpr int NFR = BN / 64;          // B-fragments per wave: 2 (BN=128) or 1 (BN=64)
    constexpr int WCH = BN / 32;          // W staging chunks: 4 or 2
    int zi = blockIdx.z;
    const short* A = ga.A[zi];
    const short* W = ga.W[zi];
    __shared__ short As[2][64 * 64];
    __shared__ short Bs[2][BN * 64];
    int t = threadIdx.x;
    int w = t >> 6, l = t & 63;
    int m0 = blockIdx.x * 64, n0 = blockIdx.y * BN;
    int wn = w * (BN / 4);

    f32x4 acc[4][NFR];
#pragma unroll
    for (int a = 0; a < 4; ++a)
#pragma unroll
        for (int b = 0; b < NFR; ++b) acc[a][b] = f32x4{0.f, 0.f, 0.f, 0.f};

    // pre-swizzled-source staging: LDS linear per wave, global addr carries the XOR
    auto STAGE = [&](int buf, int k0) {
#pragma unroll
        for (int c = 0; c < 2; ++c) {
            int g0 = c * 256 + w * 64;
            int g  = g0 + l;
            int row = g >> 3, ss = g & 7;
            int slot = ss ^ (row & 7);
            gload16(A + (size_t)(m0 + row) * K + k0 + slot * 8, &As[buf][g0 * 8]);
        }
#pragma unroll
        for (int c = 0; c < WCH; ++c) {
            int g0 = c * 256 + w * 64;
            int g  = g0 + l;
            int row = g >> 3, ss = g & 7;
            int slot = ss ^ (row & 7);
            gload16(W + (size_t)(n0 + row) * K + k0 + slot * 8, &Bs[buf][g0 * 8]);
        }
    };

    int NT = K >> 6;
    STAGE(0, 0);
    int cur = 0;
    for (int it = 0; it < NT; ++it) {
        if (it + 1 < NT) {
            STAGE(cur ^ 1, (it + 1) << 6);
            if (BN == 128) asm volatile("s_waitcnt vmcnt(6)" ::: "memory");
            else           asm volatile("s_waitcnt vmcnt(4)" ::: "memory");
        } else {
            asm volatile("s_waitcnt vmcnt(0)" ::: "memory");
        }
        __builtin_amdgcn_s_barrier();
#pragma unroll
        for (int kk = 0; kk < 2; ++kk) {
            short8 af[4], bf[NFR];
            int sl = kk * 4 + (l >> 4);
#pragma unroll
            for (int mf = 0; mf < 4; ++mf) {
                int row = mf * 16 + (l & 15);
                af[mf] = *(const short8*)(&As[cur][row * 64 + (sl ^ (row & 7)) * 8]);
            }
#pragma unroll
            for (int nf = 0; nf < NFR; ++nf) {
                int row = wn + nf * 16 + (l & 15);
                bf[nf] = *(const short8*)(&Bs[cur][row * 64 + (sl ^ (row & 7)) * 8]);
            }
#pragma unroll
            for (int mf = 0; mf < 4; ++mf)
#pragma unroll
                for (int nf = 0; nf < NFR; ++nf)
                    acc[mf][nf] = __builtin_amdgcn_mfma_f32_16x16x32_bf16(
                        af[mf], bf[nf], acc[mf][nf], 0, 0, 0);
        }
        asm volatile("s_waitcnt lgkmcnt(0)" ::: "memory");
        __builtin_amdgcn_sched_barrier(0);
        __builtin_amdgcn_s_barrier();
        cur ^= 1;
    }

    // C/D layout: col = lane&15, row = (lane>>4)*4 + reg
#pragma unroll
    for (int mf = 0; mf < 4; ++mf) {
#pragma unroll
        for (int nf = 0; nf < NFR; ++nf) {
            int col = n0 + wn + nf * 16 + (l & 15);
#pragma unroll
            for (int j = 0; j < 4; ++j) {
                int row = m0 + mf * 16 + (l >> 4) * 4 + j;
                float v = acc[mf][nf][j];
                if (EPI == 0) {
                    ((short*)ga.out[zi])[(size_t)row * N + col] = f2b(v);
                } else if (EPI == 1) {
                    v += ga.bias[zi][col] + ga.res[zi][(size_t)row * N + col];
                    ((float*)ga.out[zi])[(size_t)row * N + col] = v;
                } else if (EPI == 2) {
                    v = gelu_f(v + ga.bias[zi][col]);
                    ((short*)ga.out[zi])[(size_t)row * N + col] = f2b(v);
                }
            }
        }
    }
}

// ------- fused: conv reductions w/ inline gather (blocks 0..255, BM=64) + local attn -
struct CLArgs {
    const short* qkv_g; const short* wk; const short* wv;
    float* kpart; float* vpart;
    const short* qkv_l; short* ob;
};
__global__ __launch_bounds__(256) void convlat_k(CLArgs ga) {
    __shared__ char smem[65536];
    int t = threadIdx.x;
    if (blockIdx.x < 256) {
        int bid = blockIdx.x;
        int m0 = (bid & 15) * 64;       // 16 m-blocks of 64 rows
        int slice = (bid >> 4) & 7;     // K-slice (off value)
        int zi = bid >> 7;              // 0 = K-conv, 1 = V-conv
        const short* Abase = ga.qkv_g + (zi ? 256 : 128);
        const short* W = zi ? ga.wv : ga.wk;
        float* outp = zi ? ga.vpart : ga.kpart;
        short (*As)[64 * 64]  = (short(*)[64 * 64])smem;             // 2 x 8 KB
        short (*Bs)[128 * 64] = (short(*)[128 * 64])(smem + 16384);  // 2 x 16 KB
        int w = t >> 6, l = t & 63;
        int wn = w * 32;
        int kbeg = slice * 128;
        int od = slice >> 2, oh = (slice >> 1) & 1, ow = slice & 1;

        f32x4 acc[4][2];
#pragma unroll
        for (int a = 0; a < 4; ++a)
#pragma unroll
            for (int b = 0; b < 2; ++b) acc[a][b] = f32x4{0.f, 0.f, 0.f, 0.f};

        auto STAGE = [&](int buf, int k0) {
#pragma unroll
            for (int c = 0; c < 2; ++c) {
                int g0 = c * 256 + w * 64;
                int g  = g0 + l;
                int row = g >> 3, ss = g & 7;
                int slot = ss ^ (row & 7);
                int nr = m0 + row;
                int n = (2 * (nr >> 8) + od) * 1024 + (2 * ((nr >> 4) & 15) + oh) * 32
                        + 2 * (nr & 15) + ow;
                gload16(Abase + (size_t)n * 384 + (k0 & 127) + slot * 8, &As[buf][g0 * 8]);
            }
#pragma unroll
            for (int c = 0; c < 4; ++c) {
                int g0 = c * 256 + w * 64;
                int g  = g0 + l;
                int row = g >> 3, ss = g & 7;
                int slot = ss ^ (row & 7);
                gload16(W + (size_t)row * 1024 + k0 + slot * 8, &Bs[buf][g0 * 8]);
            }
        };

        STAGE(0, kbeg);
        int cur = 0;
        for (int it = 0; it < 2; ++it) {
            if (it == 0) {
                STAGE(1, kbeg + 64);
                asm volatile("s_waitcnt vmcnt(6)" ::: "memory");
            } else {
                asm volatile("s_waitcnt vmcnt(0)" ::: "memory");
            }
            __builtin_amdgcn_s_barrier();
#pragma unroll
            for (int kk = 0; kk < 2; ++kk) {
                short8 af[4], bf[2];
                int sl = kk * 4 + (l >> 4);
#pragma unroll
                for (int mf = 0; mf < 4; ++mf) {
                    int row = mf * 16 + (l & 15);
                    af[mf] = *(const short8*)(&As[cur][row * 64 + (sl ^ (row & 7)) * 8]);
                }
#pragma unroll
                for (int nf = 0; nf < 2; ++nf) {
                    int row = wn + nf * 16 + (l & 15);
                    bf[nf] = *(const short8*)(&Bs[cur][row * 64 + (sl ^ (row & 7)) * 8]);
                }
#pragma unroll
                for (int mf = 0; mf < 4; ++mf)
#pragma unroll
                    for (int nf = 0; nf < 2; ++nf)
                        acc[mf][nf] = __builtin_amdgcn_mfma_f32_16x16x32_bf16(
                            af[mf], bf[nf], acc[mf][nf], 0, 0, 0);
            }
            asm volatile("s_waitcnt lgkmcnt(0)" ::: "memory");
            __builtin_amdgcn_sched_barrier(0);
            __builtin_amdgcn_s_barrier();
            cur ^= 1;
        }
#pragma unroll
        for (int mf = 0; mf < 4; ++mf)
#pragma unroll
            for (int nf = 0; nf < 2; ++nf) {
                int col = wn + nf * 16 + (l & 15);
#pragma unroll
                for (int j = 0; j < 4; ++j) {
                    int row = m0 + mf * 16 + (l >> 4) * 4 + j;
                    outp[(size_t)slice * (NR * C_DIM) + (size_t)row * C_DIM + col] =
                        acc[mf][nf][j];
                }
            }
        return;
    }
    float (*ks)[32][HDIM] = (float(*)[32][HDIM])smem;
    float (*vs)[32][HDIM] = (float(*)[32][HDIM])(smem + 16384);
    int m = t & 31, h = t >> 5, r = blockIdx.x - 256;
    int zd = r >> 6, zh = (r >> 3) & 7, zw = r & 7;
    int pd = m >> 4, ph = (m >> 2) & 3, pw = m & 3;
    int n = (zd * 2 + pd) * 1024 + (zh * 4 + ph) * 32 + (zw * 4 + pw);
    const short* base = ga.qkv_l + (size_t)n * 384 + h * HDIM;
    float q[16], kt[16], vt[16];
    ld16bf(base, q);
    ld16bf(base + 128, kt);
    ld16bf(base + 256, vt);
#pragma unroll
    for (int d = 0; d < 16; ++d) { ks[h][m][d] = kt[d]; vs[h][m][d] = vt[d]; }
    __syncthreads();
    float s[32];
#pragma unroll
    for (int j = 0; j < 32; ++j) {
        float d = 0.f;
#pragma unroll
        for (int dd = 0; dd < 16; ++dd) d += q[dd] * ks[h][j][dd];
        s[j] = __expf(d * QK_SCALE);
    }
    float sum = 0.f;
#pragma unroll
    for (int j = 0; j < 32; ++j) sum += s[j];
    float inv = 1.0f / sum;
    float oo[16] = {};
#pragma unroll
    for (int j = 0; j < 32; ++j) {
        float p = s[j] * inv;
#pragma unroll
        for (int dd = 0; dd < 16; ++dd) oo[dd] += p * vs[h][j][dd];
    }
#pragma unroll
    for (int dd = 0; dd < 16; ++dd) {
        int n2 = h * 4 + (dd >> 2);
        int c2 = (dd & 3) * 32 + m;
        int pd2 = n2 >> 4, ph2 = (n2 >> 2) & 3, pw2 = n2 & 3;
        int nn = (zd * 2 + pd2) * 1024 + (zh * 4 + ph2) * 32 + (zw * 4 + pw2);
        ga.ob[(size_t)nn * C_DIM + c2] = f2b(oo[dd]);
    }
}

// ------- sum 8 split-K partials + per-head LN; K -> bf16 *0.25*log2e, V -> bf16^T ---
__global__ __launch_bounds__(256) void ln_head_sum_k(const float* __restrict__ kpart,
                                                     const float* __restrict__ vpart,
                                                     const float* __restrict__ gk, const float* __restrict__ bk,
                                                     const float* __restrict__ gv, const float* __restrict__ bv,
                                                     short* __restrict__ kout, short* __restrict__ vout) {
    __shared__ float vlds[8][16][33];
    int t = threadIdx.x;
    bool sel = blockIdx.x >= 32;
    int b = sel ? (blockIdx.x - 32) : blockIdx.x;
    int id2 = b * 256 + t;
    const float* part = sel ? vpart : kpart;
    const float* g    = sel ? gv : gk;
    const float* bb   = sel ? bv : bk;
    int nr = id2 >> 3, h = id2 & 7;
    size_t base = (size_t)nr * C_DIM + h * HDIM;
    float v[16] = {};
#pragma unroll
    for (int p = 0; p < 8; ++p) {
        const float* pp = part + (size_t)p * (NR * C_DIM) + base;
#pragma unroll
        for (int d4 = 0; d4 < 4; ++d4) {
            float4 tv = *(const float4*)(pp + d4 * 4);
            v[d4 * 4 + 0] += tv.x; v[d4 * 4 + 1] += tv.y;
            v[d4 * 4 + 2] += tv.z; v[d4 * 4 + 3] += tv.w;
        }
    }
    float s = 0.f;
#pragma unroll
    for (int i = 0; i < 16; ++i) s += v[i];
    float m = s * (1.0f / 16.0f);
    float sq = 0.f;
#pragma unroll
    for (int i = 0; i < 16; ++i) { float d = v[i] - m; sq += d * d; }
    float rs = rsqrtf(sq * (1.0f / 16.0f) + EPSV);
    if (!sel) {
        short* op = kout + (size_t)h * (NR * HDIM) + (size_t)nr * HDIM;
#pragma unroll
        for (int i = 0; i < 16; ++i)
            op[i] = f2b(((v[i] - m) * rs * g[i] + bb[i]) * QK_L2E);
        return;
    }
    int nr_l = t >> 3;               // 0..31  (h = t&7)
#pragma unroll
    for (int i = 0; i < 16; ++i)
        vlds[h][i][nr_l] = (v[i] - m) * rs * g[i] + bb[i];
    __syncthreads();
    int row = t >> 1, half = t & 1;  // 128 rows = (h2,i2); 2 threads/row
    int h2 = row >> 4, i2 = row & 15;
    const float* src = &vlds[h2][i2][half * 16];
    uint4 u0 = {pk2(src[0], src[1]), pk2(src[2], src[3]), pk2(src[4], src[5]), pk2(src[6], src[7])};
    uint4 u1 = {pk2(src[8], src[9]), pk2(src[10], src[11]), pk2(src[12], src[13]), pk2(src[14], src[15])};
    short* dst = vout + (size_t)h2 * (HDIM * NR) + (size_t)i2 * NR + b * 32 + half * 16;
    *(uint4*)(dst)     = u0;
    *(uint4*)(dst + 8) = u1;
}

// ---------------- global attention v8: 8 waves, split-K wave pairs ----------------
__global__ __launch_bounds__(512) void gattn_k(const short* __restrict__ qkv,
                                               const short* __restrict__ kb,   // [8][1024][16] *0.25*log2e
                                               const short* __restrict__ vt,   // [8][16][1024]
                                               short* __restrict__ ob) {
    __shared__ short plds[8][2048];
    __shared__ float comb[4][64][5];
    int t = threadIdx.x;
    int w = t >> 6, l = t & 63;
    int h = blockIdx.y;
    int lr = l & 15, lq = l >> 4;
    int qw = w & 3, kw = w >> 2;
    int q0 = blockIdx.x * 64 + qw * 16;

    short8 qf = short8{0, 0, 0, 0, 0, 0, 0, 0};
    if (lq < 2)
        qf = *(const short8*)(qkv + (size_t)(q0 + lr) * 384 + h * HDIM + lq * 8);

    const short* kh = kb + (size_t)h * (NR * HDIM);
    const short* vh = vt + (size_t)h * (HDIM * NR);
    short* pw = &plds[w][0];

    const f32x4 zz = {0.f, 0.f, 0.f, 0.f};
    f32x4 oacc = {0.f, 0.f, 0.f, 0.f};
    float rs = 0.f;

    for (int c = 0; c < 4; ++c) {
        int kbase = kw * 512 + c * 128;
        f32x4 s[8];
#pragma unroll
        for (int nf = 0; nf < 8; ++nf) {
            short8 kf = short8{0, 0, 0, 0, 0, 0, 0, 0};
            if (lq < 2)
                kf = *(const short8*)(kh + (size_t)(kbase + nf * 16 + lr) * HDIM + lq * 8);
            s[nf] = __builtin_amdgcn_mfma_f32_16x16x32_bf16(kf, qf, zz, 0, 0, 0);
        }
#pragma unroll
        for (int nf = 0; nf < 8; ++nf) {
            float p0 = exp2f(s[nf][0]);
            float p1 = exp2f(s[nf][1]);
            float p2 = exp2f(s[nf][2]);
            float p3 = exp2f(s[nf][3]);
            rs += (p0 + p1) + (p2 + p3);
            unsigned int u01, u23;
            asm("v_cvt_pk_bf16_f32 %0, %1, %2" : "=v"(u01) : "v"(p0), "v"(p1));
            asm("v_cvt_pk_bf16_f32 %0, %1, %2" : "=v"(u23) : "v"(p2), "v"(p3));
            int k0 = nf * 16 + lq * 4;
            int sw = (lr & 7) << 3;
            *(unsigned int*)&pw[lr * 128 + (k0 ^ sw)]       = u01;
            *(unsigned int*)&pw[lr * 128 + ((k0 + 2) ^ sw)] = u23;
        }
#pragma unroll
        for (int ks = 0; ks < 4; ++ks) {
            short8 pf = *(const short8*)&pw[(lr * 128 + ks * 32 + lq * 8) ^ ((lr & 7) << 3)];
            short8 vf = *(const short8*)(vh + (size_t)lr * NR + kbase + ks * 32 + lq * 8);
            oacc = __builtin_amdgcn_mfma_f32_16x16x32_bf16(pf, vf, oacc, 0, 0, 0);
        }
    }
    rs += __shfl_xor(rs, 16);
    rs += __shfl_xor(rs, 32);
    if (w >= 4) {
        comb[w - 4][l][0] = oacc[0];
        comb[w - 4][l][1] = oacc[1];
        comb[w - 4][l][2] = oacc[2];
        comb[w - 4][l][3] = oacc[3];
        comb[w - 4][l][4] = rs;
    }
    __syncthreads();
    if (w < 4) {
        oacc[0] += comb[w][l][0];
        oacc[1] += comb[w][l][1];
        oacc[2] += comb[w][l][2];
        oacc[3] += comb[w][l][3];
        rs += comb[w][l][4];
        float r0 = __shfl(rs, lq * 4 + 0);
        float r1 = __shfl(rs, lq * 4 + 1);
        float r2 = __shfl(rs, lq * 4 + 2);
        float r3 = __shfl(rs, lq * 4 + 3);
        size_t base_o = (size_t)(q0 + lq * 4) * C_DIM + h * HDIM + lr;
        ob[base_o]             = f2b(oacc[0] / r0);
        ob[base_o + C_DIM]     = f2b(oacc[1] / r1);
        ob[base_o + 2 * C_DIM] = f2b(oacc[2] / r2);
        ob[base_o + 3 * C_DIM] = f2b(oacc[3] / r3);
    }
}

// ---------------- final gate: out(C,N) = x * sigmoid(loc + glo) ----------------
__global__ __launch_bounds__(256) void gate_k(const float* __restrict__ x,
                                              const float* __restrict__ lf, const float* __restrict__ gf,
                                              float* __restrict__ out) {
    __shared__ float tile[32][33];
    int n0 = blockIdx.x * 32, c0 = blockIdx.y * 32;
    int tx = threadIdx.x, ty = threadIdx.y;
#pragma unroll
    for (int k = 0; k < 4; ++k) {
        int n = n0 + ty + k * 8, c = c0 + tx;
        tile[ty + k * 8][tx] = lf[(size_t)n * C_DIM + c] + gf[(size_t)n * C_DIM + c];
    }
    __syncthreads();
#pragma unroll
    for (int k = 0; k < 4; ++k) {
        int c = c0 + ty + k * 8, n = n0 + tx;
        float z = tile[tx][ty + k * 8];
        float sg = 1.0f / (1.0f + __expf(-z));
        out[(size_t)c * N_TOK + n] = x[(size_t)c * N_TOK + n] * sg;
    }
}

extern "C" void kernel_launch(void* const* d_in, const int* in_sizes, int n_in,
                              void* d_out, int out_size, void* d_ws, size_t ws_size,
                              hipStream_t stream) {
    const float* x        = (const float*)d_in[0];
    const float* l_n1_g   = (const float*)d_in[1];
    const float* l_n1_b   = (const float*)d_in[2];
    const float* l_qkv_w  = (const float*)d_in[3];
    const float* l_proj_w = (const float*)d_in[4];
    const float* l_proj_b = (const float*)d_in[5];
    const float* l_n2_g   = (const float*)d_in[6];
    const float* l_n2_b   = (const float*)d_in[7];
    const float* l_fc1_w  = (const float*)d_in[8];
    const float* l_fc1_b  = (const float*)d_in[9];
    const float* l_fc2_w  = (const float*)d_in[10];
    const float* l_fc2_b  = (const float*)d_in[11];
    const float* g_n1_g   = (const float*)d_in[12];
    const float* g_n1_b   = (const float*)d_in[13];
    const float* g_qkv_w  = (const float*)d_in[14];
    const float* g_proj_w = (const float*)d_in[15];
    const float* g_proj_b = (const float*)d_in[16];
    const float* g_n2_g   = (const float*)d_in[17];
    const float* g_n2_b   = (const float*)d_in[18];
    const float* g_fc1_w  = (const float*)d_in[19];
    const float* g_fc1_b  = (const float*)d_in[20];
    const float* g_fc2_w  = (const float*)d_in[21];
    const float* g_fc2_b  = (const float*)d_in[22];
    const float* g_ke_w   = (const float*)d_in[23];
    const float* g_ve_w   = (const float*)d_in[24];
    const float* g_nk_g   = (const float*)d_in[25];
    const float* g_nk_b   = (const float*)d_in[26];
    const float* g_nv_g   = (const float*)d_in[27];
    const float* g_nv_b   = (const float*)d_in[28];
    float* out = (float*)d_out;

    char* base = (char*)d_ws;
    float* xt     = (float*)(base);                        // 0-4 MB
    float* t1_l   = (float*)(base + (4ull  << 20));        // 4-8 MB
    float* t1_g   = (float*)(base + (8ull  << 20));        // 8-12 MB
    short* yA16   = (short*)(base + (12ull << 20));        // 12-14 (later t2_l)
    short* yG16   = (short*)(base + (14ull << 20));        // 14-16 (later t2_g)
    short* t2_l   = yA16;
    short* t2_g   = yG16;
    float* locfin = (float*)(base + (12ull << 20));        // 12-16 (after fc1 reads t2)
    short* obuf_l = (short*)(base + (16ull << 20));        // 16-18
    short* obuf_g = (short*)(base + (18ull << 20));        // 18-20
    float* glofin = (float*)(base + (16ull << 20));        // 16-20 (after proj reads obuf)
    short* qkv_l  = (short*)(base + (20ull << 20));        // 20-26
    short* qkv_g  = (short*)(base + (26ull << 20));        // 26-32
    short* h1_l   = (short*)(base + (32ull << 20));        // 32-40 (after ln_head)
    float* kpart  = (float*)(base + (32ull << 20));        // 32-36 (pre-fc1)
    float* vpart  = (float*)(base + (36ull << 20));        // 36-40 (pre-fc1)
    short* h1_g   = (short*)(base + (40ull << 20));        // 40-48
    short* kb16   = (short*)(base + (48ull << 20));        // [8][1024][16]
    short* vt16   = (short*)(base + (48ull << 20) + (512ull << 10)); // [8][16][1024]
    short* wts    = (short*)(base + (49ull << 20));        // ~1.3 MB

    const int L_QKV = 0,      L_PROJ = 49152, L_FC1 = 65536,  L_FC2 = 131072;
    const int G_QKV = 196608, G_PROJ = 245760, G_FC1 = 262144, G_FC2 = 327680;
    const int G_KE  = 393216, G_VE   = 524288;

    CvtArgs ca;
    ca.d[0] = {l_qkv_w,  wts + L_QKV,  49152, 0};
    ca.d[1] = {l_proj_w, wts + L_PROJ, 16384, 0};
    ca.d[2] = {l_fc1_w,  wts + L_FC1,  65536, 0};
    ca.d[3] = {l_fc2_w,  wts + L_FC2,  65536, 0};
    ca.d[4] = {g_qkv_w,  wts + G_QKV,  49152, 0};
    ca.d[5] = {g_proj_w, wts + G_PROJ, 16384, 0};
    ca.d[6] = {g_fc1_w,  wts + G_FC1,  65536, 0};
    ca.d[7] = {g_fc2_w,  wts + G_FC2,  65536, 0};
    ca.d[8] = {g_ke_w,   wts + G_KE,  131072, 1};   // permuted: [co][off*128+ci]
    ca.d[9] = {g_ve_w,   wts + G_VE,  131072, 1};

    // 1: transpose + LN1 + weight cvt (fused)
    prep_k<<<296, 256, 0, stream>>>(x, l_n1_g, l_n1_b, g_n1_g, g_n1_b, xt, yA16, yG16, ca);

    // 2: both qkv GEMMs (768 blocks)
    MArgs a_qkv = {{yA16, yG16}, {wts + L_QKV, wts + G_QKV}, {nullptr, nullptr}, {nullptr, nullptr}, {qkv_l, qkv_g}};
    mgemm_k<0, 128><<<dim3(128, 3, 2), 256, 0, stream>>>(a_qkv, N_TOK, 384, 128);

    // 3: conv reductions (BM=64, inline gather, split-K x8) + local attention (512 blocks)
    CLArgs cla = {qkv_g, wts + G_KE, wts + G_VE, kpart, vpart, qkv_l, obuf_l};
    convlat_k<<<512, 256, 0, stream>>>(cla);

    // 4: head-LN for K (scaled for exp2) and V^T (coalesced via LDS transpose)
    ln_head_sum_k<<<64, 256, 0, stream>>>(kpart, vpart, g_nk_g, g_nk_b, g_nv_g, g_nv_b, kb16, vt16);

    // 5: global attention (MFMA flash v8)
    gattn_k<<<dim3(128, 8), 512, 0, stream>>>(qkv_g, kb16, vt16, obuf_g);

    // 6: both proj GEMMs (+bias+residual) (BN=64 -> 512 blocks)
    MArgs a_pj = {{obuf_l, obuf_g}, {wts + L_PROJ, wts + G_PROJ}, {l_proj_b, g_proj_b}, {xt, xt}, {t1_l, t1_g}};
    mgemm_k<1, 64><<<dim3(128, 2, 2), 256, 0, stream>>>(a_pj, N_TOK, 128, 128);

    // 7: both second LNs
    ln2_pair_k<<<4096, 256, 0, stream>>>(t1_l, l_n2_g, l_n2_b, t2_l, t1_g, g_n2_g, g_n2_b, t2_g);

    // 8: both fc1 GEMMs (+bias+gelu) (1024 blocks)
    MArgs a_f1 = {{t2_l, t2_g}, {wts + L_FC1, wts + G_FC1}, {l_fc1_b, g_fc1_b}, {nullptr, nullptr}, {h1_l, h1_g}};
    mgemm_k<2, 128><<<dim3(128, 4, 2), 256, 0, stream>>>(a_f1, N_TOK, 512, 128);

    // 9: both fc2 GEMMs (+bias+residual) (BN=64 -> 512 blocks)
    MArgs a_f2 = {{h1_l, h1_g}, {wts + L_FC2, wts + G_FC2}, {l_fc2_b, g_fc2_b}, {t1_l, t1_g}, {locfin, glofin}};
    mgemm_k<1, 64><<<dim3(128, 2, 2), 256, 0, stream>>>(a_f2, N_TOK, 128, 512);

    // 10: gate
    gate_k<<<dim3(256, 4), dim3(32, 8), 0, stream>>>(x, locfin, glofin, out);
}

// Round 16
// 119.460 us; speedup vs baseline: 1.4635x; 1.0085x over previous
//
#include <hip/hip_runtime.h>
#include <math.h>

#define N_TOK 8192
#define C_DIM 128
#define NHD   8
#define HDIM  16
#define NR    1024
#define EPSV  1e-5f
#define QK_SCALE 0.25f
#define QK_L2E  0.36067376f   /* 0.25 * log2(e) */

typedef __attribute__((ext_vector_type(8))) short short8;
typedef __attribute__((ext_vector_type(4))) float f32x4;

__device__ __forceinline__ float gelu_f(float v) {
    float u = 0.7978845608f * (v + 0.044715f * v * v * v);
    float e = exp2f(2.885390082f * u);
    return v * (e / (e + 1.0f));
}
__device__ __forceinline__ float uaf(unsigned int u) {
    union { unsigned int u; float f; } x; x.u = u; return x.f;
}
__device__ __forceinline__ short f2b(float v) {
    union { float f; unsigned int u; } x; x.f = v;
    unsigned int r = x.u + 0x7fffu + ((x.u >> 16) & 1u);
    return (short)(r >> 16);
}
__device__ __forceinline__ unsigned int pk2(float a, float b) {
    return (unsigned int)(unsigned short)f2b(a) | ((unsigned int)(unsigned short)f2b(b) << 16);
}
__device__ __forceinline__ void ld16bf(const short* p, float* d) {
    uint4 a = *(const uint4*)p;
    uint4 b = *(const uint4*)(p + 8);
    d[0]  = uaf(a.x << 16); d[1]  = uaf(a.x & 0xffff0000u);
    d[2]  = uaf(a.y << 16); d[3]  = uaf(a.y & 0xffff0000u);
    d[4]  = uaf(a.z << 16); d[5]  = uaf(a.z & 0xffff0000u);
    d[6]  = uaf(a.w << 16); d[7]  = uaf(a.w & 0xffff0000u);
    d[8]  = uaf(b.x << 16); d[9]  = uaf(b.x & 0xffff0000u);
    d[10] = uaf(b.y << 16); d[11] = uaf(b.y & 0xffff0000u);
    d[12] = uaf(b.z << 16); d[13] = uaf(b.z & 0xffff0000u);
    d[14] = uaf(b.w << 16); d[15] = uaf(b.w & 0xffff0000u);
}

// async global->LDS, 16B per lane; LDS dest = wave-uniform base + lane*16
__device__ __forceinline__ void gload16(const void* g, void* l) {
    __builtin_amdgcn_global_load_lds(
        (const __attribute__((address_space(1))) unsigned int*)g,
        (__attribute__((address_space(3))) unsigned int*)l, 16, 0, 0);
}

struct CvtDesc { const float* src; short* dst; int n; int pad; };
struct CvtArgs { CvtDesc d[10]; };

// ------- fused: transpose+LN1 (blocks 0..255) + weight cvt (blocks 256..295) --------
__global__ __launch_bounds__(256) void prep_k(const float* __restrict__ x,
                                              const float* __restrict__ g1, const float* __restrict__ b1,
                                              const float* __restrict__ g2, const float* __restrict__ b2,
                                              float* __restrict__ xt,
                                              short* __restrict__ o1, short* __restrict__ o2,
                                              CvtArgs ca) {
    __shared__ float tile[32][132];
    int t = threadIdx.x;
    if (blockIdx.x >= 256) {
        int bid = blockIdx.x - 256;   // 0..39
#pragma unroll 1
        for (int d = 0; d < 10; ++d) {
            CvtDesc dd = ca.d[d];
            if (dd.pad) {
                for (int i = bid * 256 + t; i < dd.n; i += 40 * 256) {
                    int co = i >> 10, qq = i & 1023;
                    dd.dst[co * 1024 + ((qq & 7) << 7) + (qq >> 3)] = f2b(dd.src[i]);
                }
            } else {
                for (int i = bid * 256 + t; i < dd.n; i += 40 * 256)
                    dd.dst[i] = f2b(dd.src[i]);
            }
        }
        return;
    }
    int n0 = blockIdx.x * 32;
#pragma unroll
    for (int k = 0; k < 16; ++k) {
        int f = t + k * 256;
        int n = f & 31, c = f >> 5;
        tile[n][c] = x[(size_t)c * N_TOK + n0 + n];
    }
    __syncthreads();
    int tk = t >> 3, cb = (t & 7) * 16;
    float v[16];
    float s = 0.f, sq = 0.f;
#pragma unroll
    for (int i = 0; i < 16; ++i) {
        v[i] = tile[tk][cb + i];
        s += v[i]; sq += v[i] * v[i];
    }
    s += __shfl_xor(s, 1);  s += __shfl_xor(s, 2);  s += __shfl_xor(s, 4);
    sq += __shfl_xor(sq, 1); sq += __shfl_xor(sq, 2); sq += __shfl_xor(sq, 4);
    float m = s * (1.0f / 128.0f);
    float var = sq * (1.0f / 128.0f) - m * m;
    float rs = rsqrtf(var + EPSV);
    int tok = n0 + tk;
    float* xp = xt + (size_t)tok * C_DIM + cb;
    *(float4*)(xp)      = make_float4(v[0], v[1], v[2], v[3]);
    *(float4*)(xp + 4)  = make_float4(v[4], v[5], v[6], v[7]);
    *(float4*)(xp + 8)  = make_float4(v[8], v[9], v[10], v[11]);
    *(float4*)(xp + 12) = make_float4(v[12], v[13], v[14], v[15]);
    float hA[16], hB[16];
#pragma unroll
    for (int i = 0; i < 16; ++i) {
        float hn = (v[i] - m) * rs;
        hA[i] = hn * g1[cb + i] + b1[cb + i];
        hB[i] = hn * g2[cb + i] + b2[cb + i];
    }
    uint4 ua0 = {pk2(hA[0], hA[1]), pk2(hA[2], hA[3]), pk2(hA[4], hA[5]), pk2(hA[6], hA[7])};
    uint4 ua1 = {pk2(hA[8], hA[9]), pk2(hA[10], hA[11]), pk2(hA[12], hA[13]), pk2(hA[14], hA[15])};
    uint4 ub0 = {pk2(hB[0], hB[1]), pk2(hB[2], hB[3]), pk2(hB[4], hB[5]), pk2(hB[6], hB[7])};
    uint4 ub1 = {pk2(hB[8], hB[9]), pk2(hB[10], hB[11]), pk2(hB[12], hB[13]), pk2(hB[14], hB[15])};
    *(uint4*)(o1 + (size_t)tok * C_DIM + cb)     = ua0;
    *(uint4*)(o1 + (size_t)tok * C_DIM + cb + 8) = ua1;
    *(uint4*)(o2 + (size_t)tok * C_DIM + cb)     = ub0;
    *(uint4*)(o2 + (size_t)tok * C_DIM + cb + 8) = ub1;
}

// ---------------- second LN, paired across branches ----------------
__global__ __launch_bounds__(256) void ln2_pair_k(const float* __restrict__ in0,
                                                  const float* __restrict__ g0, const float* __restrict__ b0,
                                                  short* __restrict__ o0,
                                                  const float* __restrict__ in1,
                                                  const float* __restrict__ g1, const float* __restrict__ b1,
                                                  short* __restrict__ o1) {
    int blk = blockIdx.x;
    bool sel = blk >= 2048;
    blk &= 2047;
    const float* in = sel ? in1 : in0;
    const float* g  = sel ? g1 : g0;
    const float* b  = sel ? b1 : b0;
    short* o        = sel ? o1 : o0;
    int lane = threadIdx.x & 63;
    int n = blk * 4 + (threadIdx.x >> 6);
    float v0 = in[(size_t)n * C_DIM + lane];
    float v1 = in[(size_t)n * C_DIM + 64 + lane];
    float s = v0 + v1, sq = v0 * v0 + v1 * v1;
#pragma unroll
    for (int off = 32; off >= 1; off >>= 1) {
        s += __shfl_xor(s, off);
        sq += __shfl_xor(sq, off);
    }
    float m = s * (1.0f / 128.0f);
    float var = sq * (1.0f / 128.0f) - m * m;
    float rs = rsqrtf(var + EPSV);
    o[(size_t)n * C_DIM + lane]      = f2b((v0 - m) * rs * g[lane] + b[lane]);
    o[(size_t)n * C_DIM + 64 + lane] = f2b((v1 - m) * rs * g[lane + 64] + b[lane + 64]);
}

// ---------------- bf16 MFMA GEMM, BM=64 x BN={128,64} tile, async 2-phase -----------
// 4 waves, each 64 x (BN/4); grid = (M/64, N/BN, 2).
// EPI: 0 bf16 out; 1 f32 = acc+bias+res; 2 bf16 = gelu(acc+bias)
struct MArgs {
    const short* A[2]; const short* W[2];
    const float* bias[2]; const float* res[2];
    void* out[2];
};
template <int EPI, int BN>
__global__ __launch_bounds__(256) void mgemm_k(MArgs ga, int M, int N, int K) {
    constexpr int NFR = BN / 64;          // B-fragments per wave: 2 (BN=128) or 1 (BN=64)
    constexpr int WCH = BN / 32;          // W staging chunks: 4 or 2
    int zi = blockIdx.z;
    const short* A = ga.A[zi];
    const short* W = ga.W[zi];
    __shared__ short As[2][64 * 64];
    __shared__ short Bs[2][BN * 64];
    int t = threadIdx.x;
    int w = t >> 6, l = t & 63;
    int m0 = blockIdx.x * 64, n0 = blockIdx.y * BN;
    int wn = w * (BN / 4);

    f32x4 acc[4][NFR];
#pragma unroll
    for (int a = 0; a < 4; ++a)
#pragma unroll
        for (int b = 0; b < NFR; ++b) acc[a][b] = f32x4{0.f, 0.f, 0.f, 0.f};

    // pre-swizzled-source staging: LDS linear per wave, global addr carries the XOR
    auto STAGE = [&](int buf, int k0) {
#pragma unroll
        for (int c = 0; c < 2; ++c) {
            int g0 = c * 256 + w * 64;
            int g  = g0 + l;
            int row = g >> 3, ss = g & 7;
            int slot = ss ^ (row & 7);
            gload16(A + (size_t)(m0 + row) * K + k0 + slot * 8, &As[buf][g0 * 8]);
        }
#pragma unroll
        for (int c = 0; c < WCH; ++c) {
            int g0 = c * 256 + w * 64;
            int g  = g0 + l;
            int row = g >> 3, ss = g & 7;
            int slot = ss ^ (row & 7);
            gload16(W + (size_t)(n0 + row) * K + k0 + slot * 8, &Bs[buf][g0 * 8]);
        }
    };

    int NT = K >> 6;
    STAGE(0, 0);
    int cur = 0;
    for (int it = 0; it < NT; ++it) {
        if (it + 1 < NT) {
            STAGE(cur ^ 1, (it + 1) << 6);
            if (BN == 128) asm volatile("s_waitcnt vmcnt(6)" ::: "memory");
            else           asm volatile("s_waitcnt vmcnt(4)" ::: "memory");
        } else {
            asm volatile("s_waitcnt vmcnt(0)" ::: "memory");
        }
        __builtin_amdgcn_s_barrier();
#pragma unroll
        for (int kk = 0; kk < 2; ++kk) {
            short8 af[4], bf[NFR];
            int sl = kk * 4 + (l >> 4);
#pragma unroll
            for (int mf = 0; mf < 4; ++mf) {
                int row = mf * 16 + (l & 15);
                af[mf] = *(const short8*)(&As[cur][row * 64 + (sl ^ (row & 7)) * 8]);
            }
#pragma unroll
            for (int nf = 0; nf < NFR; ++nf) {
                int row = wn + nf * 16 + (l & 15);
                bf[nf] = *(const short8*)(&Bs[cur][row * 64 + (sl ^ (row & 7)) * 8]);
            }
#pragma unroll
            for (int mf = 0; mf < 4; ++mf)
#pragma unroll
                for (int nf = 0; nf < NFR; ++nf)
                    acc[mf][nf] = __builtin_amdgcn_mfma_f32_16x16x32_bf16(
                        af[mf], bf[nf], acc[mf][nf], 0, 0, 0);
        }
        asm volatile("s_waitcnt lgkmcnt(0)" ::: "memory");
        __builtin_amdgcn_sched_barrier(0);
        __builtin_amdgcn_s_barrier();
        cur ^= 1;
    }

    // C/D layout: col = lane&15, row = (lane>>4)*4 + reg
#pragma unroll
    for (int mf = 0; mf < 4; ++mf) {
#pragma unroll
        for (int nf = 0; nf < NFR; ++nf) {
            int col = n0 + wn + nf * 16 + (l & 15);
#pragma unroll
            for (int j = 0; j < 4; ++j) {
                int row = m0 + mf * 16 + (l >> 4) * 4 + j;
                float v = acc[mf][nf][j];
                if (EPI == 0) {
                    ((short*)ga.out[zi])[(size_t)row * N + col] = f2b(v);
                } else if (EPI == 1) {
                    v += ga.bias[zi][col] + ga.res[zi][(size_t)row * N + col];
                    ((float*)ga.out[zi])[(size_t)row * N + col] = v;
                } else if (EPI == 2) {
                    v = gelu_f(v + ga.bias[zi][col]);
                    ((short*)ga.out[zi])[(size_t)row * N + col] = f2b(v);
                }
            }
        }
    }
}

// ------- fused: conv reductions w/ inline gather (blocks 0..255, BM=64) + local attn -
struct CLArgs {
    const short* qkv_g; const short* wk; const short* wv;
    float* kpart; float* vpart;
    const short* qkv_l; short* ob;
};
__global__ __launch_bounds__(256) void convlat_k(CLArgs ga) {
    __shared__ char smem[65536];
    int t = threadIdx.x;
    if (blockIdx.x < 256) {
        int bid = blockIdx.x;
        int m0 = (bid & 15) * 64;       // 16 m-blocks of 64 rows
        int slice = (bid >> 4) & 7;     // K-slice (off value)
        int zi = bid >> 7;              // 0 = K-conv, 1 = V-conv
        const short* Abase = ga.qkv_g + (zi ? 256 : 128);
        const short* W = zi ? ga.wv : ga.wk;
        float* outp = zi ? ga.vpart : ga.kpart;
        short (*As)[64 * 64]  = (short(*)[64 * 64])smem;             // 2 x 8 KB
        short (*Bs)[128 * 64] = (short(*)[128 * 64])(smem + 16384);  // 2 x 16 KB
        int w = t >> 6, l = t & 63;
        int wn = w * 32;
        int kbeg = slice * 128;
        int od = slice >> 2, oh = (slice >> 1) & 1, ow = slice & 1;

        f32x4 acc[4][2];
#pragma unroll
        for (int a = 0; a < 4; ++a)
#pragma unroll
            for (int b = 0; b < 2; ++b) acc[a][b] = f32x4{0.f, 0.f, 0.f, 0.f};

        auto STAGE = [&](int buf, int k0) {
#pragma unroll
            for (int c = 0; c < 2; ++c) {
                int g0 = c * 256 + w * 64;
                int g  = g0 + l;
                int row = g >> 3, ss = g & 7;
                int slot = ss ^ (row & 7);
                int nr = m0 + row;
                int n = (2 * (nr >> 8) + od) * 1024 + (2 * ((nr >> 4) & 15) + oh) * 32
                        + 2 * (nr & 15) + ow;
                gload16(Abase + (size_t)n * 384 + (k0 & 127) + slot * 8, &As[buf][g0 * 8]);
            }
#pragma unroll
            for (int c = 0; c < 4; ++c) {
                int g0 = c * 256 + w * 64;
                int g  = g0 + l;
                int row = g >> 3, ss = g & 7;
                int slot = ss ^ (row & 7);
                gload16(W + (size_t)row * 1024 + k0 + slot * 8, &Bs[buf][g0 * 8]);
            }
        };

        STAGE(0, kbeg);
        int cur = 0;
        for (int it = 0; it < 2; ++it) {
            if (it == 0) {
                STAGE(1, kbeg + 64);
                asm volatile("s_waitcnt vmcnt(6)" ::: "memory");
            } else {
                asm volatile("s_waitcnt vmcnt(0)" ::: "memory");
            }
            __builtin_amdgcn_s_barrier();
#pragma unroll
            for (int kk = 0; kk < 2; ++kk) {
                short8 af[4], bf[2];
                int sl = kk * 4 + (l >> 4);
#pragma unroll
                for (int mf = 0; mf < 4; ++mf) {
                    int row = mf * 16 + (l & 15);
                    af[mf] = *(const short8*)(&As[cur][row * 64 + (sl ^ (row & 7)) * 8]);
                }
#pragma unroll
                for (int nf = 0; nf < 2; ++nf) {
                    int row = wn + nf * 16 + (l & 15);
                    bf[nf] = *(const short8*)(&Bs[cur][row * 64 + (sl ^ (row & 7)) * 8]);
                }
#pragma unroll
                for (int mf = 0; mf < 4; ++mf)
#pragma unroll
                    for (int nf = 0; nf < 2; ++nf)
                        acc[mf][nf] = __builtin_amdgcn_mfma_f32_16x16x32_bf16(
                            af[mf], bf[nf], acc[mf][nf], 0, 0, 0);
            }
            asm volatile("s_waitcnt lgkmcnt(0)" ::: "memory");
            __builtin_amdgcn_sched_barrier(0);
            __builtin_amdgcn_s_barrier();
            cur ^= 1;
        }
#pragma unroll
        for (int mf = 0; mf < 4; ++mf)
#pragma unroll
            for (int nf = 0; nf < 2; ++nf) {
                int col = wn + nf * 16 + (l & 15);
#pragma unroll
                for (int j = 0; j < 4; ++j) {
                    int row = m0 + mf * 16 + (l >> 4) * 4 + j;
                    outp[(size_t)slice * (NR * C_DIM) + (size_t)row * C_DIM + col] =
                        acc[mf][nf][j];
                }
            }
        return;
    }
    float (*ks)[32][HDIM] = (float(*)[32][HDIM])smem;
    float (*vs)[32][HDIM] = (float(*)[32][HDIM])(smem + 16384);
    int m = t & 31, h = t >> 5, r = blockIdx.x - 256;
    int zd = r >> 6, zh = (r >> 3) & 7, zw = r & 7;
    int pd = m >> 4, ph = (m >> 2) & 3, pw = m & 3;
    int n = (zd * 2 + pd) * 1024 + (zh * 4 + ph) * 32 + (zw * 4 + pw);
    const short* base = ga.qkv_l + (size_t)n * 384 + h * HDIM;
    float q[16], kt[16], vt[16];
    ld16bf(base, q);
    ld16bf(base + 128, kt);
    ld16bf(base + 256, vt);
#pragma unroll
    for (int d = 0; d < 16; ++d) { ks[h][m][d] = kt[d]; vs[h][m][d] = vt[d]; }
    __syncthreads();
    float s[32];
#pragma unroll
    for (int j = 0; j < 32; ++j) {
        float d = 0.f;
#pragma unroll
        for (int dd = 0; dd < 16; ++dd) d += q[dd] * ks[h][j][dd];
        s[j] = __expf(d * QK_SCALE);
    }
    float sum = 0.f;
#pragma unroll
    for (int j = 0; j < 32; ++j) sum += s[j];
    float inv = 1.0f / sum;
    float oo[16] = {};
#pragma unroll
    for (int j = 0; j < 32; ++j) {
        float p = s[j] * inv;
#pragma unroll
        for (int dd = 0; dd < 16; ++dd) oo[dd] += p * vs[h][j][dd];
    }
#pragma unroll
    for (int dd = 0; dd < 16; ++dd) {
        int n2 = h * 4 + (dd >> 2);
        int c2 = (dd & 3) * 32 + m;
        int pd2 = n2 >> 4, ph2 = (n2 >> 2) & 3, pw2 = n2 & 3;
        int nn = (zd * 2 + pd2) * 1024 + (zh * 4 + ph2) * 32 + (zw * 4 + pw2);
        ga.ob[(size_t)nn * C_DIM + c2] = f2b(oo[dd]);
    }
}

// ------- sum 8 split-K partials + per-head LN; K -> bf16 *0.25*log2e, V -> bf16^T ---
// blocks 0..127: K path (4 threads/item); blocks 128..191: V path (2 threads/item).
__global__ __launch_bounds__(256) void ln_head_sum_k(const float* __restrict__ kpart,
                                                     const float* __restrict__ vpart,
                                                     const float* __restrict__ gk, const float* __restrict__ bk,
                                                     const float* __restrict__ gv, const float* __restrict__ bv,
                                                     short* __restrict__ kout, short* __restrict__ vout) {
    __shared__ float vlds[8][16][17];
    int t = threadIdx.x;
    if (blockIdx.x < 128) {
        // K path: 64 items/block, 4 threads per item (2 partials each)
        int id = blockIdx.x * 64 + (t >> 2);
        int sub = t & 3;
        int nr = id >> 3, h = id & 7;
        size_t base = (size_t)nr * C_DIM + h * HDIM;
        float v[16] = {};
#pragma unroll
        for (int pp = 0; pp < 2; ++pp) {
            const float* src = kpart + (size_t)(sub * 2 + pp) * (NR * C_DIM) + base;
#pragma unroll
            for (int d4 = 0; d4 < 4; ++d4) {
                float4 tv = *(const float4*)(src + d4 * 4);
                v[d4 * 4 + 0] += tv.x; v[d4 * 4 + 1] += tv.y;
                v[d4 * 4 + 2] += tv.z; v[d4 * 4 + 3] += tv.w;
            }
        }
#pragma unroll
        for (int i = 0; i < 16; ++i) {
            v[i] += __shfl_xor(v[i], 1);
            v[i] += __shfl_xor(v[i], 2);
        }
        float s = 0.f;
#pragma unroll
        for (int i = 0; i < 16; ++i) s += v[i];
        float m = s * (1.0f / 16.0f);
        float sq = 0.f;
#pragma unroll
        for (int i = 0; i < 16; ++i) { float d = v[i] - m; sq += d * d; }
        float rs = rsqrtf(sq * (1.0f / 16.0f) + EPSV);
        int i0 = sub * 4;
        float o0 = ((v[i0 + 0] - m) * rs * gk[i0 + 0] + bk[i0 + 0]) * QK_L2E;
        float o1 = ((v[i0 + 1] - m) * rs * gk[i0 + 1] + bk[i0 + 1]) * QK_L2E;
        float o2 = ((v[i0 + 2] - m) * rs * gk[i0 + 2] + bk[i0 + 2]) * QK_L2E;
        float o3 = ((v[i0 + 3] - m) * rs * gk[i0 + 3] + bk[i0 + 3]) * QK_L2E;
        uint2 u = {pk2(o0, o1), pk2(o2, o3)};
        *(uint2*)(kout + (size_t)h * (NR * HDIM) + (size_t)nr * HDIM + i0) = u;
        return;
    }
    // V path: 128 items/block, 2 threads per item (4 partials each)
    int b = blockIdx.x - 128;            // 0..63; nr range [b*16, b*16+16)
    int idv = b * 128 + (t >> 1);
    int sub = t & 1;
    int nr = idv >> 3, h = idv & 7;
    int nr_l = (t >> 1) >> 3;            // 0..15
    size_t base = (size_t)nr * C_DIM + h * HDIM;
    float v[16] = {};
#pragma unroll
    for (int pp = 0; pp < 4; ++pp) {
        const float* src = vpart + (size_t)(sub * 4 + pp) * (NR * C_DIM) + base;
#pragma unroll
        for (int d4 = 0; d4 < 4; ++d4) {
            float4 tv = *(const float4*)(src + d4 * 4);
            v[d4 * 4 + 0] += tv.x; v[d4 * 4 + 1] += tv.y;
            v[d4 * 4 + 2] += tv.z; v[d4 * 4 + 3] += tv.w;
        }
    }
#pragma unroll
    for (int i = 0; i < 16; ++i) v[i] += __shfl_xor(v[i], 1);
    float s = 0.f;
#pragma unroll
    for (int i = 0; i < 16; ++i) s += v[i];
    float m = s * (1.0f / 16.0f);
    float sq = 0.f;
#pragma unroll
    for (int i = 0; i < 16; ++i) { float d = v[i] - m; sq += d * d; }
    float rs = rsqrtf(sq * (1.0f / 16.0f) + EPSV);
#pragma unroll
    for (int i = 0; i < 8; ++i) {
        int ii = sub * 8 + i;
        vlds[h][ii][nr_l] = (v[ii] - m) * rs * gv[ii] + bv[ii];
    }
    __syncthreads();
    int row = t >> 1, half = t & 1;      // 128 rows = (h2,i2); 2 threads/row
    int h2 = row >> 4, i2 = row & 15;
    const float* src = &vlds[h2][i2][half * 8];
    uint4 u = {pk2(src[0], src[1]), pk2(src[2], src[3]),
               pk2(src[4], src[5]), pk2(src[6], src[7])};
    short* dst = vout + (size_t)h2 * (HDIM * NR) + (size_t)i2 * NR + b * 16 + half * 8;
    *(uint4*)(dst) = u;
}

// ---------------- global attention v8: 8 waves, split-K wave pairs ----------------
__global__ __launch_bounds__(512) void gattn_k(const short* __restrict__ qkv,
                                               const short* __restrict__ kb,   // [8][1024][16] *0.25*log2e
                                               const short* __restrict__ vt,   // [8][16][1024]
                                               short* __restrict__ ob) {
    __shared__ short plds[8][2048];
    __shared__ float comb[4][64][5];
    int t = threadIdx.x;
    int w = t >> 6, l = t & 63;
    int h = blockIdx.y;
    int lr = l & 15, lq = l >> 4;
    int qw = w & 3, kw = w >> 2;
    int q0 = blockIdx.x * 64 + qw * 16;

    short8 qf = short8{0, 0, 0, 0, 0, 0, 0, 0};
    if (lq < 2)
        qf = *(const short8*)(qkv + (size_t)(q0 + lr) * 384 + h * HDIM + lq * 8);

    const short* kh = kb + (size_t)h * (NR * HDIM);
    const short* vh = vt + (size_t)h * (HDIM * NR);
    short* pw = &plds[w][0];

    const f32x4 zz = {0.f, 0.f, 0.f, 0.f};
    f32x4 oacc = {0.f, 0.f, 0.f, 0.f};
    float rs = 0.f;

    for (int c = 0; c < 4; ++c) {
        int kbase = kw * 512 + c * 128;
        f32x4 s[8];
#pragma unroll
        for (int nf = 0; nf < 8; ++nf) {
            short8 kf = short8{0, 0, 0, 0, 0, 0, 0, 0};
            if (lq < 2)
                kf = *(const short8*)(kh + (size_t)(kbase + nf * 16 + lr) * HDIM + lq * 8);
            s[nf] = __builtin_amdgcn_mfma_f32_16x16x32_bf16(kf, qf, zz, 0, 0, 0);
        }
#pragma unroll
        for (int nf = 0; nf < 8; ++nf) {
            float p0 = exp2f(s[nf][0]);
            float p1 = exp2f(s[nf][1]);
            float p2 = exp2f(s[nf][2]);
            float p3 = exp2f(s[nf][3]);
            rs += (p0 + p1) + (p2 + p3);
            unsigned int u01, u23;
            asm("v_cvt_pk_bf16_f32 %0, %1, %2" : "=v"(u01) : "v"(p0), "v"(p1));
            asm("v_cvt_pk_bf16_f32 %0, %1, %2" : "=v"(u23) : "v"(p2), "v"(p3));
            int k0 = nf * 16 + lq * 4;
            int sw = (lr & 7) << 3;
            *(unsigned int*)&pw[lr * 128 + (k0 ^ sw)]       = u01;
            *(unsigned int*)&pw[lr * 128 + ((k0 + 2) ^ sw)] = u23;
        }
#pragma unroll
        for (int ks = 0; ks < 4; ++ks) {
            short8 pf = *(const short8*)&pw[(lr * 128 + ks * 32 + lq * 8) ^ ((lr & 7) << 3)];
            short8 vf = *(const short8*)(vh + (size_t)lr * NR + kbase + ks * 32 + lq * 8);
            oacc = __builtin_amdgcn_mfma_f32_16x16x32_bf16(pf, vf, oacc, 0, 0, 0);
        }
    }
    rs += __shfl_xor(rs, 16);
    rs += __shfl_xor(rs, 32);
    if (w >= 4) {
        comb[w - 4][l][0] = oacc[0];
        comb[w - 4][l][1] = oacc[1];
        comb[w - 4][l][2] = oacc[2];
        comb[w - 4][l][3] = oacc[3];
        comb[w - 4][l][4] = rs;
    }
    __syncthreads();
    if (w < 4) {
        oacc[0] += comb[w][l][0];
        oacc[1] += comb[w][l][1];
        oacc[2] += comb[w][l][2];
        oacc[3] += comb[w][l][3];
        rs += comb[w][l][4];
        float r0 = __shfl(rs, lq * 4 + 0);
        float r1 = __shfl(rs, lq * 4 + 1);
        float r2 = __shfl(rs, lq * 4 + 2);
        float r3 = __shfl(rs, lq * 4 + 3);
        size_t base_o = (size_t)(q0 + lq * 4) * C_DIM + h * HDIM + lr;
        ob[base_o]             = f2b(oacc[0] / r0);
        ob[base_o + C_DIM]     = f2b(oacc[1] / r1);
        ob[base_o + 2 * C_DIM] = f2b(oacc[2] / r2);
        ob[base_o + 3 * C_DIM] = f2b(oacc[3] / r3);
    }
}

// ---------------- final gate: out(C,N) = x * sigmoid(loc + glo) ----------------
__global__ __launch_bounds__(256) void gate_k(const float* __restrict__ x,
                                              const float* __restrict__ lf, const float* __restrict__ gf,
                                              float* __restrict__ out) {
    __shared__ float tile[32][33];
    int n0 = blockIdx.x * 32, c0 = blockIdx.y * 32;
    int tx = threadIdx.x, ty = threadIdx.y;
#pragma unroll
    for (int k = 0; k < 4; ++k) {
        int n = n0 + ty + k * 8, c = c0 + tx;
        tile[ty + k * 8][tx] = lf[(size_t)n * C_DIM + c] + gf[(size_t)n * C_DIM + c];
    }
    __syncthreads();
#pragma unroll
    for (int k = 0; k < 4; ++k) {
        int c = c0 + ty + k * 8, n = n0 + tx;
        float z = tile[tx][ty + k * 8];
        float sg = 1.0f / (1.0f + __expf(-z));
        out[(size_t)c * N_TOK + n] = x[(size_t)c * N_TOK + n] * sg;
    }
}

extern "C" void kernel_launch(void* const* d_in, const int* in_sizes, int n_in,
                              void* d_out, int out_size, void* d_ws, size_t ws_size,
                              hipStream_t stream) {
    const float* x        = (const float*)d_in[0];
    const float* l_n1_g   = (const float*)d_in[1];
    const float* l_n1_b   = (const float*)d_in[2];
    const float* l_qkv_w  = (const float*)d_in[3];
    const float* l_proj_w = (const float*)d_in[4];
    const float* l_proj_b = (const float*)d_in[5];
    const float* l_n2_g   = (const float*)d_in[6];
    const float* l_n2_b   = (const float*)d_in[7];
    const float* l_fc1_w  = (const float*)d_in[8];
    const float* l_fc1_b  = (const float*)d_in[9];
    const float* l_fc2_w  = (const float*)d_in[10];
    const float* l_fc2_b  = (const float*)d_in[11];
    const float* g_n1_g   = (const float*)d_in[12];
    const float* g_n1_b   = (const float*)d_in[13];
    const float* g_qkv_w  = (const float*)d_in[14];
    const float* g_proj_w = (const float*)d_in[15];
    const float* g_proj_b = (const float*)d_in[16];
    const float* g_n2_g   = (const float*)d_in[17];
    const float* g_n2_b   = (const float*)d_in[18];
    const float* g_fc1_w  = (const float*)d_in[19];
    const float* g_fc1_b  = (const float*)d_in[20];
    const float* g_fc2_w  = (const float*)d_in[21];
    const float* g_fc2_b  = (const float*)d_in[22];
    const float* g_ke_w   = (const float*)d_in[23];
    const float* g_ve_w   = (const float*)d_in[24];
    const float* g_nk_g   = (const float*)d_in[25];
    const float* g_nk_b   = (const float*)d_in[26];
    const float* g_nv_g   = (const float*)d_in[27];
    const float* g_nv_b   = (const float*)d_in[28];
    float* out = (float*)d_out;

    char* base = (char*)d_ws;
    float* xt     = (float*)(base);                        // 0-4 MB
    float* t1_l   = (float*)(base + (4ull  << 20));        // 4-8 MB
    float* t1_g   = (float*)(base + (8ull  << 20));        // 8-12 MB
    short* yA16   = (short*)(base + (12ull << 20));        // 12-14 (later t2_l)
    short* yG16   = (short*)(base + (14ull << 20));        // 14-16 (later t2_g)
    short* t2_l   = yA16;
    short* t2_g   = yG16;
    float* locfin = (float*)(base + (12ull << 20));        // 12-16 (after fc1 reads t2)
    short* obuf_l = (short*)(base + (16ull << 20));        // 16-18
    short* obuf_g = (short*)(base + (18ull << 20));        // 18-20
    float* glofin = (float*)(base + (16ull << 20));        // 16-20 (after proj reads obuf)
    short* qkv_l  = (short*)(base + (20ull << 20));        // 20-26
    short* qkv_g  = (short*)(base + (26ull << 20));        // 26-32
    short* h1_l   = (short*)(base + (32ull << 20));        // 32-40 (after ln_head)
    float* kpart  = (float*)(base + (32ull << 20));        // 32-36 (pre-fc1)
    float* vpart  = (float*)(base + (36ull << 20));        // 36-40 (pre-fc1)
    short* h1_g   = (short*)(base + (40ull << 20));        // 40-48
    short* kb16   = (short*)(base + (48ull << 20));        // [8][1024][16]
    short* vt16   = (short*)(base + (48ull << 20) + (512ull << 10)); // [8][16][1024]
    short* wts    = (short*)(base + (49ull << 20));        // ~1.3 MB

    const int L_QKV = 0,      L_PROJ = 49152, L_FC1 = 65536,  L_FC2 = 131072;
    const int G_QKV = 196608, G_PROJ = 245760, G_FC1 = 262144, G_FC2 = 327680;
    const int G_KE  = 393216, G_VE   = 524288;

    CvtArgs ca;
    ca.d[0] = {l_qkv_w,  wts + L_QKV,  49152, 0};
    ca.d[1] = {l_proj_w, wts + L_PROJ, 16384, 0};
    ca.d[2] = {l_fc1_w,  wts + L_FC1,  65536, 0};
    ca.d[3] = {l_fc2_w,  wts + L_FC2,  65536, 0};
    ca.d[4] = {g_qkv_w,  wts + G_QKV,  49152, 0};
    ca.d[5] = {g_proj_w, wts + G_PROJ, 16384, 0};
    ca.d[6] = {g_fc1_w,  wts + G_FC1,  65536, 0};
    ca.d[7] = {g_fc2_w,  wts + G_FC2,  65536, 0};
    ca.d[8] = {g_ke_w,   wts + G_KE,  131072, 1};   // permuted: [co][off*128+ci]
    ca.d[9] = {g_ve_w,   wts + G_VE,  131072, 1};

    // 1: transpose + LN1 + weight cvt (fused)
    prep_k<<<296, 256, 0, stream>>>(x, l_n1_g, l_n1_b, g_n1_g, g_n1_b, xt, yA16, yG16, ca);

    // 2: both qkv GEMMs (BN=64 -> 1536 blocks)
    MArgs a_qkv = {{yA16, yG16}, {wts + L_QKV, wts + G_QKV}, {nullptr, nullptr}, {nullptr, nullptr}, {qkv_l, qkv_g}};
    mgemm_k<0, 64><<<dim3(128, 6, 2), 256, 0, stream>>>(a_qkv, N_TOK, 384, 128);

    // 3: conv reductions (BM=64, inline gather, split-K x8) + local attention (512 blocks)
    CLArgs cla = {qkv_g, wts + G_KE, wts + G_VE, kpart, vpart, qkv_l, obuf_l};
    convlat_k<<<512, 256, 0, stream>>>(cla);

    // 4: head-LN for K and V^T (192 blocks: K 4-way split, V 2-way split)
    ln_head_sum_k<<<192, 256, 0, stream>>>(kpart, vpart, g_nk_g, g_nk_b, g_nv_g, g_nv_b, kb16, vt16);

    // 5: global attention (MFMA flash v8)
    gattn_k<<<dim3(128, 8), 512, 0, stream>>>(qkv_g, kb16, vt16, obuf_g);

    // 6: both proj GEMMs (+bias+residual) (BN=64 -> 512 blocks)
    MArgs a_pj = {{obuf_l, obuf_g}, {wts + L_PROJ, wts + G_PROJ}, {l_proj_b, g_proj_b}, {xt, xt}, {t1_l, t1_g}};
    mgemm_k<1, 64><<<dim3(128, 2, 2), 256, 0, stream>>>(a_pj, N_TOK, 128, 128);

    // 7: both second LNs
    ln2_pair_k<<<4096, 256, 0, stream>>>(t1_l, l_n2_g, l_n2_b, t2_l, t1_g, g_n2_g, g_n2_b, t2_g);

    // 8: both fc1 GEMMs (+bias+gelu) (BN=64 -> 2048 blocks)
    MArgs a_f1 = {{t2_l, t2_g}, {wts + L_FC1, wts + G_FC1}, {l_fc1_b, g_fc1_b}, {nullptr, nullptr}, {h1_l, h1_g}};
    mgemm_k<2, 64><<<dim3(128, 8, 2), 256, 0, stream>>>(a_f1, N_TOK, 512, 128);

    // 9: both fc2 GEMMs (+bias+residual) (BN=64 -> 512 blocks)
    MArgs a_f2 = {{h1_l, h1_g}, {wts + L_FC2, wts + G_FC2}, {l_fc2_b, g_fc2_b}, {t1_l, t1_g}, {locfin, glofin}};
    mgemm_k<1, 64><<<dim3(128, 2, 2), 256, 0, stream>>>(a_f2, N_TOK, 128, 512);

    // 10: gate
    gate_k<<<dim3(256, 4), dim3(32, 8), 0, stream>>>(x, locfin, glofin, out);
}